// Round 13
// baseline (285.412 us; speedup 1.0000x reference)
//
#include <hip/hip_runtime.h>
#include <hip/hip_bf16.h>

#define NNODES 100000
#define NEDGES 1600000
#define NF 256
#define NH 128
#define SCAN_ELEMS 1024
#define SCAN_NBLK ((NNODES + SCAN_ELEMS - 1) / SCAN_ELEMS)   // 98

// LDS-privatized histogram / fill parameters
#define HG 200                     // workgroups (chunks)
#define HCHUNK (NEDGES / HG)       // 8000 edges per WG
#define HBINS 25000                // nodes per pass
#define HR 4                       // passes (4 * 25000 = 100000)
#define HWORDS (NNODES / 2)        // 50000 packed words per partial slice

#define WPREP_BLOCKS 129           // (NF*NH + NH + 255)/256

typedef _Float16 half4v __attribute__((ext_vector_type(4)));
typedef _Float16 half8v __attribute__((ext_vector_type(8)));
typedef float floatx16 __attribute__((ext_vector_type(16)));

// k-permutation within each 16-block so MFMA f16 fragments (k = g*4 + (j&3) + 8*(j>>2))
// are 8 contiguous halves in storage. perm: [0,1,2,3, 8,9,10,11, 4,5,6,7, 12,13,14,15]
__device__ __forceinline__ int pos16(int k) {        // logical k (0..15) -> storage pos
    return (((k >> 2) & 1) << 3) + (k & 3) + (((k >> 3) & 1) << 2);
}
__device__ __forceinline__ int ipos16(int p) {       // storage pos -> logical k
    int g = (p >> 3) & 1, j = p & 7;
    return g * 4 + (j & 3) + ((j >> 2) << 3);
}

__device__ __forceinline__ float2 h2f2(unsigned u) {
    union { unsigned u; _Float16 h[2]; } c; c.u = u;
    return make_float2((float)c.h[0], (float)c.h[1]);
}

// ---------------- LDS-privatized degree histogram ---------------------------
__global__ __launch_bounds__(512)
void hist_part_kernel(const int* __restrict__ src, const int* __restrict__ dst,
                      unsigned* __restrict__ partial) {
    __shared__ unsigned lds[HBINS / 2];        // 12500 words = 50 KB
    const int g = blockIdx.x, t = threadIdx.x;
    const int e0 = g * HCHUNK;
    for (int r = 0; r < HR; ++r) {
        const int lo = r * HBINS;
        for (int i = t; i < HBINS / 2; i += 512) lds[i] = 0;
        __syncthreads();
        for (int i = t; i < HCHUNK; i += 512) {
            unsigned us = (unsigned)(src[e0 + i] - lo);
            if (us < HBINS) atomicAdd(&lds[us >> 1], 1u << ((us & 1) * 16));
            unsigned ud = (unsigned)(dst[e0 + i] - lo);
            if (ud < HBINS) atomicAdd(&lds[ud >> 1], 1u << ((ud & 1) * 16 + 8));
        }
        __syncthreads();
        unsigned* dp = partial + (size_t)g * HWORDS + (lo >> 1);
        for (int i = t; i < HBINS / 2; i += 512) dp[i] = lds[i];
        __syncthreads();
    }
}

// ---------------- fused: per-chunk exclusive scan + degree reduce + norms ----
__global__ __launch_bounds__(256)
void degscan_kernel(const unsigned* __restrict__ partial,
                    unsigned char* __restrict__ offb,
                    float* __restrict__ ns, float* __restrict__ nd,
                    int* __restrict__ cnt_in) {
    int w = blockIdx.x * 256 + threadIdx.x;
    if (w >= HWORDS) return;
    unsigned o0 = 0, i0 = 0, o1 = 0, i1 = 0;
    for (int g = 0; g < HG; ++g) {
        unsigned v = partial[(size_t)g * HWORDS + w];
        unsigned char* ob = offb + (size_t)g * NNODES;
        ob[2 * w]     = (unsigned char)i0;     // exclusive running in-degree
        ob[2 * w + 1] = (unsigned char)i1;
        o0 += v & 0xffu;         i0 += (v >> 8) & 0xffu;
        o1 += (v >> 16) & 0xffu; i1 += v >> 24;
    }
    int n0 = 2 * w, n1 = 2 * w + 1;
    ns[n0] = rsqrtf((float)max((int)o0, 1));
    nd[n0] = rsqrtf((float)max((int)i0, 1));
    cnt_in[n0] = (int)i0;
    ns[n1] = rsqrtf((float)max((int)o1, 1));
    nd[n1] = rsqrtf((float)max((int)i1, 1));
    cnt_in[n1] = (int)i1;
}

// ---------------- 3-pass exclusive scan over cnt_in -> row_ptr --------------
__global__ __launch_bounds__(256)
void scanA_kernel(const int* __restrict__ cnt, int* __restrict__ pre,
                  int* __restrict__ bsum, int n) {
    __shared__ int tsum[256];
    int b = blockIdx.x, t = threadIdx.x;
    int base = b * SCAN_ELEMS + t * 4;
    int v[4]; int s = 0;
    #pragma unroll
    for (int k = 0; k < 4; ++k) { int idx = base + k; v[k] = (idx < n) ? cnt[idx] : 0; s += v[k]; }
    tsum[t] = s;
    __syncthreads();
    for (int off = 1; off < 256; off <<= 1) {
        int val = (t >= off) ? tsum[t - off] : 0;
        __syncthreads();
        tsum[t] += val;
        __syncthreads();
    }
    int run = (t == 0) ? 0 : tsum[t - 1];
    #pragma unroll
    for (int k = 0; k < 4; ++k) { int idx = base + k; if (idx < n) pre[idx] = run; run += v[k]; }
    if (t == 255) bsum[b] = tsum[255];
}

__global__ __launch_bounds__(128)
void scanB_kernel(int* __restrict__ bsum, int nb, int* __restrict__ row_ptr) {
    __shared__ int s[128];
    int t = threadIdx.x;
    int v = (t < nb) ? bsum[t] : 0;
    s[t] = v;
    __syncthreads();
    for (int off = 1; off < 128; off <<= 1) {
        int u = (t >= off) ? s[t - off] : 0;
        __syncthreads();
        s[t] += u;
        __syncthreads();
    }
    if (t < nb) bsum[t] = s[t] - v;           // exclusive block sums
    if (t == 0) row_ptr[NNODES] = NEDGES;
}

__global__ __launch_bounds__(256)
void scanC_kernel(int* __restrict__ pre, const int* __restrict__ bsum, int n) {
    int add = bsum[blockIdx.x];
    int base = blockIdx.x * SCAN_ELEMS + threadIdx.x;
    #pragma unroll
    for (int k = 0; k < 4; ++k) {
        int idx = base + k * 256;
        if (idx < n) pre[idx] += add;
    }
}

// ---------------- atomic-free bucket fill -----------------------------------
__global__ __launch_bounds__(512)
void fill_kernel(const int* __restrict__ src, const int* __restrict__ dst,
                 const int* __restrict__ row_ptr, const unsigned char* __restrict__ offb,
                 int* __restrict__ col) {
    __shared__ unsigned lcur[HBINS / 2];       // 12500 words, 2x16-bit counters
    const int g = blockIdx.x, t = threadIdx.x;
    const int e0 = g * HCHUNK;
    const unsigned char* ob = offb + (size_t)g * NNODES;
    for (int r = 0; r < HR; ++r) {
        const int lo = r * HBINS;
        for (int i = t; i < HBINS / 2; i += 512) lcur[i] = 0;
        __syncthreads();
        for (int i = t; i < HCHUNK; i += 512) {
            int d = dst[e0 + i];
            unsigned ud = (unsigned)(d - lo);
            if (ud < HBINS) {
                unsigned prev = atomicAdd(&lcur[ud >> 1], 1u << ((ud & 1) * 16));
                unsigned rank = (prev >> ((ud & 1) * 16)) & 0xffffu;
                int p = row_ptr[d] + (int)ob[d] + (int)rank;
                col[p] = src[e0 + i];
            }
        }
        __syncthreads();
    }
}

// ---------------- weight prep: W1 transpose+perm, b1 perm, v2 = W2@Wfc, c0 --
__global__ __launch_bounds__(256)
void prep_w_kernel(const float* __restrict__ W1, const float* __restrict__ b1,
                   _Float16* __restrict__ Wt1, float* __restrict__ b1p,
                   const float* __restrict__ W2, const float* __restrict__ Wfc,
                   const float* __restrict__ b2, const float* __restrict__ bfc,
                   float* __restrict__ v2p, float* __restrict__ c0) {
    int b = blockIdx.x, t = threadIdx.x;
    if (b < WPREP_BLOCKS) {
        int id = b * 256 + t;
        if (id < NF * NH) {                    // W1 -> Wt1[n][perm(k)] f16
            int k = id >> 7, n = id & 127;
            Wt1[(size_t)n * NF + (k & ~15) + pos16(k & 15)] = (_Float16)W1[id];
        } else if (id < NF * NH + NH) {
            int pos = id - NF * NH;
            int k = (pos & ~15) + ipos16(pos & 15);
            b1p[pos] = b1[k];
        }
    } else {
        // v2 = W2 @ Wfc (perm order), c0 = b2.Wfc + bfc
        if (t < 128) {
            float s = 0.f;
            #pragma unroll 16
            for (int j = 0; j < 128; ++j) s += W2[t * 128 + j] * Wfc[j];
            v2p[(t & ~15) + pos16(t & 15)] = s;
        } else if (t < 192) {
            int lane = t - 128;
            float c = b2[lane] * Wfc[lane] + b2[lane + 64] * Wfc[lane + 64];
            #pragma unroll
            for (int off = 32; off > 0; off >>= 1) c += __shfl_down(c, off);
            if (lane == 0) c0[0] = c + bfc[0];
        }
    }
}

// ---------------- fused GEMM1: C = (x @ W1) * ns, LDS-free ------------------
// A fragments loaded straight from global f32 x into VGPRs (4x float4/lane/kk,
// per-lane row stride 1 KB; L1/L2 absorb the 2x same-wr duplication), converted
// to f16 in-register. B from L2-resident Wt1 (perm layout). No __shared__, no
// barriers: waves pipeline independently, occupancy capped only by VGPRs.
__global__ __launch_bounds__(256)
void gemm1_kernel(const float* __restrict__ X, const _Float16* __restrict__ Wt,
                  const float* __restrict__ norm_s, _Float16* __restrict__ Cout,
                  int N) {
    const int tid = threadIdx.x;
    const int l = tid & 63, w = tid >> 6;
    const int wr = w >> 1, wc = w & 1;         // 2x2 wave grid, 64x64 per wave
    const int row0 = blockIdx.x * 128;
    const int g = l >> 5;

    const int r0 = row0 + wr * 64 + (l & 31);  // a0 row
    const int r1 = r0 + 32;                    // a1 row
    const float* A0 = X + (size_t)min(r0, N - 1) * NF;   // clamp: never stored
    const float* A1 = X + (size_t)min(r1, N - 1) * NF;
    const _Float16* Bb = Wt + (size_t)(wc * 64 + (l & 31)) * NF + g * 8;

    floatx16 acc[2][2] = {};
    #pragma unroll 4
    for (int kk = 0; kk < 16; ++kk) {
        const int f0 = kk * 16 + g * 4;        // k = f0+0..3 (j0-3), f0+8..11 (j4-7)
        float4 a0l = *(const float4*)(A0 + f0);
        float4 a0h = *(const float4*)(A0 + f0 + 8);
        float4 a1l = *(const float4*)(A1 + f0);
        float4 a1h = *(const float4*)(A1 + f0 + 8);
        half8v a0 = { (_Float16)a0l.x, (_Float16)a0l.y, (_Float16)a0l.z, (_Float16)a0l.w,
                      (_Float16)a0h.x, (_Float16)a0h.y, (_Float16)a0h.z, (_Float16)a0h.w };
        half8v a1 = { (_Float16)a1l.x, (_Float16)a1l.y, (_Float16)a1l.z, (_Float16)a1l.w,
                      (_Float16)a1h.x, (_Float16)a1h.y, (_Float16)a1h.z, (_Float16)a1h.w };
        const _Float16* bp = Bb + kk * 16;
        half8v b0 = *(const half8v*)bp;
        half8v b1 = *(const half8v*)(bp + (size_t)32 * NF);
        acc[0][0] = __builtin_amdgcn_mfma_f32_32x32x16_f16(a0, b0, acc[0][0], 0, 0, 0);
        acc[0][1] = __builtin_amdgcn_mfma_f32_32x32x16_f16(a0, b1, acc[0][1], 0, 0, 0);
        acc[1][0] = __builtin_amdgcn_mfma_f32_32x32x16_f16(a1, b0, acc[1][0], 0, 0, 0);
        acc[1][1] = __builtin_amdgcn_mfma_f32_32x32x16_f16(a1, b1, acc[1][1], 0, 0, 0);
    }

    // epilogue: D row = (r&3)+8*(r>>2)+4*(l>>5), col = l&31; scale by ns[row]
    const int cpos = pos16(l & 15);
    const int chi = ((l >> 4) & 1) << 4;
    #pragma unroll
    for (int m = 0; m < 2; ++m) {
        #pragma unroll
        for (int r = 0; r < 16; ++r) {
            int rloc = wr * 64 + m * 32 + (r & 3) + ((r >> 2) << 3) + ((l >> 5) << 2);
            int grow = row0 + rloc;
            if (grow < N) {
                float s = norm_s[grow];
                #pragma unroll
                for (int n = 0; n < 2; ++n) {
                    int colbase = wc * 64 + n * 32 + chi;
                    Cout[(size_t)grow * NH + colbase + cpos] = (_Float16)(acc[m][n][r] * s);
                }
            }
        }
    }
}

// ---------------- fused gather + layer-1 epilogue + z-dot, one wave/node ----
// z[w] = dot(relu(agg*nd + b1p)*ns, v2p); unroll-16, scalarized row_ptr
__global__ __launch_bounds__(512)
void gatherz_kernel(const _Float16* __restrict__ m, const int* __restrict__ row_ptr,
                    const int* __restrict__ col, const float* __restrict__ norm_d,
                    const float* __restrict__ norm_s, const float* __restrict__ b1p,
                    const float* __restrict__ v2p, float* __restrict__ z, int N) {
    int w = (blockIdx.x * 512 + threadIdx.x) >> 6;
    int lane = threadIdx.x & 63;
    if (w >= N) return;
    int beg = __builtin_amdgcn_readfirstlane(row_ptr[w]);
    int end = __builtin_amdgcn_readfirstlane(row_ptr[w + 1]);
    const unsigned* mu = (const unsigned*)m + lane;  // lane's column slot
    float ax = 0.f, ay = 0.f;
    int i = beg;
    for (; i + 15 < end; i += 16) {
        unsigned u[16];
        #pragma unroll
        for (int j = 0; j < 16; ++j) u[j] = mu[(size_t)col[i + j] * 64];
        #pragma unroll
        for (int j = 0; j < 16; ++j) { float2 v = h2f2(u[j]); ax += v.x; ay += v.y; }
    }
    for (; i + 3 < end; i += 4) {
        unsigned u[4];
        #pragma unroll
        for (int j = 0; j < 4; ++j) u[j] = mu[(size_t)col[i + j] * 64];
        #pragma unroll
        for (int j = 0; j < 4; ++j) { float2 v = h2f2(u[j]); ax += v.x; ay += v.y; }
    }
    for (; i < end; ++i) {
        float2 v = h2f2(mu[(size_t)col[i] * 64]);
        ax += v.x; ay += v.y;
    }
    float nd = norm_d[w], ns = norm_s[w];
    float2 bv = ((const float2*)b1p)[lane];
    float hx = fmaxf(fmaf(ax, nd, bv.x), 0.f) * ns;
    float hy = fmaxf(fmaf(ay, nd, bv.y), 0.f) * ns;
    float2 w2 = ((const float2*)v2p)[lane];
    float p = fmaf(hx, w2.x, hy * w2.y);
    #pragma unroll
    for (int off = 32; off > 0; off >>= 1) p += __shfl_down(p, off);
    if (lane == 0) z[w] = p;
}

// ---------------- scalar CSR sum: out[w] = nd*sum z[col] + c0 ---------------
__global__ __launch_bounds__(256)
void outsum_kernel(const float* __restrict__ z, const int* __restrict__ row_ptr,
                   const int* __restrict__ col, const float* __restrict__ norm_d,
                   const float* __restrict__ c0, float* __restrict__ out, int N) {
    int w = blockIdx.x * 256 + threadIdx.x;
    if (w >= N) return;
    int beg = row_ptr[w], end = row_ptr[w + 1];
    float s0 = 0.f, s1 = 0.f, s2 = 0.f, s3 = 0.f;
    int i = beg;
    for (; i + 3 < end; i += 4) {
        s0 += z[col[i]];     s1 += z[col[i + 1]];
        s2 += z[col[i + 2]]; s3 += z[col[i + 3]];
    }
    for (; i < end; ++i) s0 += z[col[i]];
    out[w] = norm_d[w] * ((s0 + s1) + (s2 + s3)) + c0[0];
}

extern "C" void kernel_launch(void* const* d_in, const int* in_sizes, int n_in,
                              void* d_out, int out_size, void* d_ws, size_t ws_size,
                              hipStream_t stream) {
    const float* x   = (const float*)d_in[0];
    const float* W1  = (const float*)d_in[1];
    const float* b1  = (const float*)d_in[2];
    const float* W2  = (const float*)d_in[3];
    const float* b2  = (const float*)d_in[4];
    const float* Wfc = (const float*)d_in[5];
    const float* bfc = (const float*)d_in[6];
    const int*   src = (const int*)d_in[7];
    const int*   dst = (const int*)d_in[8];
    float* out = (float*)d_out;

    const int N = NNODES, E = NEDGES;

    // workspace layout (all offsets 16B-aligned)
    char* p = (char*)d_ws;
    float*    norm_s = (float*)p;      p += (size_t)N * 4;
    float*    norm_d = (float*)p;      p += (size_t)N * 4;
    _Float16* bufA_h = (_Float16*)p;   p += (size_t)N * NH * 2;   // m1 (25.6 MB)
    _Float16* Wt1    = (_Float16*)p;   p += (size_t)NF * NH * 2;
    float*    b1p    = (float*)p;      p += NH * 4;
    float*    v2p    = (float*)p;      p += NH * 4;
    float*    c0     = (float*)p;      p += 16;
    float*    z      = (float*)p;      p += (size_t)N * 4;
    int*      cnt_in = (int*)p;        p += (size_t)N * 4;
    int*      row_ptr= (int*)p;        p += (size_t)(N + 1) * 4 + 12;  // keep 16B align
    int*      col    = (int*)p;        p += (size_t)E * 4;
    int*      bsum   = (int*)p;        p += 128 * 4;
    unsigned* partial= (unsigned*)p;   // HG * HWORDS * 4 = 40 MB
    // offb (20 MB) aliases bufA_h (25.6 MB): dead before gemm1 writes bufA_h.
    unsigned char* offb = (unsigned char*)bufA_h;

    // ---- CSR build + norms + weight prep (zero global atomics) ----
    hist_part_kernel<<<HG, 512, 0, stream>>>(src, dst, partial);
    degscan_kernel<<<(HWORDS + 255) / 256, 256, 0, stream>>>(partial, offb, norm_s, norm_d, cnt_in);
    scanA_kernel<<<SCAN_NBLK, 256, 0, stream>>>(cnt_in, row_ptr, bsum, N);
    scanB_kernel<<<1, 128, 0, stream>>>(bsum, SCAN_NBLK, row_ptr);
    scanC_kernel<<<SCAN_NBLK, 256, 0, stream>>>(row_ptr, bsum, N);
    fill_kernel<<<HG, 512, 0, stream>>>(src, dst, row_ptr, offb, col);
    prep_w_kernel<<<WPREP_BLOCKS + 1, 256, 0, stream>>>(W1, b1, Wt1, b1p,
                                                        W2, Wfc, b2, bfc, v2p, c0);

    // ---- layer 1 GEMM (convx fused, LDS-free): m1 = (x @ W1) * ns ----
    gemm1_kernel<<<(N + 127) / 128, 256, 0, stream>>>(x, Wt1, norm_s, bufA_h, N);
    // ---- fused: agg1 -> h -> z (layer 2 collapsed into v2 dot) ----
    gatherz_kernel<<<((size_t)N * 64 + 511) / 512, 512, 0, stream>>>(
        bufA_h, row_ptr, col, norm_d, norm_s, b1p, v2p, z, N);
    // ---- out[w] = nd * sum z[col] + c0 ----
    outsum_kernel<<<(N + 255) / 256, 256, 0, stream>>>(z, row_ptr, col, norm_d, c0, out, N);
}

// Round 14
// 260.895 us; speedup vs baseline: 1.0940x; 1.0940x over previous
//
#include <hip/hip_runtime.h>
#include <hip/hip_bf16.h>

#define NNODES 100000
#define NEDGES 1600000
#define NF 256
#define NH 128
#define SCAN_ELEMS 1024
#define SCAN_NBLK ((NNODES + SCAN_ELEMS - 1) / SCAN_ELEMS)   // 98

// LDS-privatized histogram / fill parameters
#define HG 200                     // workgroups (chunks)
#define HCHUNK (NEDGES / HG)       // 8000 edges per WG
#define HBINS 25000                // nodes per pass
#define HR 4                       // passes (4 * 25000 = 100000)
#define HWORDS (NNODES / 2)        // 50000 packed words per partial slice

#define WPREP_BLOCKS 129           // (NF*NH + NH + 255)/256

typedef _Float16 half4v __attribute__((ext_vector_type(4)));
typedef _Float16 half8v __attribute__((ext_vector_type(8)));
typedef float floatx16 __attribute__((ext_vector_type(16)));

// k-permutation within each 16-block so MFMA f16 fragments (k = g*4 + (j&3) + 8*(j>>2))
// are 8 contiguous halves in storage. perm: [0,1,2,3, 8,9,10,11, 4,5,6,7, 12,13,14,15]
__device__ __forceinline__ int pos16(int k) {        // logical k (0..15) -> storage pos
    return (((k >> 2) & 1) << 3) + (k & 3) + (((k >> 3) & 1) << 2);
}
__device__ __forceinline__ int ipos16(int p) {       // storage pos -> logical k
    int g = (p >> 3) & 1, j = p & 7;
    return g * 4 + (j & 3) + ((j >> 2) << 3);
}

__device__ __forceinline__ float2 h2f2(unsigned u) {
    union { unsigned u; _Float16 h[2]; } c; c.u = u;
    return make_float2((float)c.h[0], (float)c.h[1]);
}

// async global->LDS DMA, 16 B per lane; LDS dest = wave base + lane*16 (linear)
__device__ __forceinline__ void load_lds16(const void* g, void* l) {
    __builtin_amdgcn_global_load_lds(
        (const __attribute__((address_space(1))) void*)g,
        (__attribute__((address_space(3))) void*)l, 16, 0, 0);
}

// ---------------- LDS-privatized degree histogram ---------------------------
__global__ __launch_bounds__(512)
void hist_part_kernel(const int* __restrict__ src, const int* __restrict__ dst,
                      unsigned* __restrict__ partial) {
    __shared__ unsigned lds[HBINS / 2];        // 12500 words = 50 KB
    const int g = blockIdx.x, t = threadIdx.x;
    const int e0 = g * HCHUNK;
    for (int r = 0; r < HR; ++r) {
        const int lo = r * HBINS;
        for (int i = t; i < HBINS / 2; i += 512) lds[i] = 0;
        __syncthreads();
        for (int i = t; i < HCHUNK; i += 512) {
            unsigned us = (unsigned)(src[e0 + i] - lo);
            if (us < HBINS) atomicAdd(&lds[us >> 1], 1u << ((us & 1) * 16));
            unsigned ud = (unsigned)(dst[e0 + i] - lo);
            if (ud < HBINS) atomicAdd(&lds[ud >> 1], 1u << ((ud & 1) * 16 + 8));
        }
        __syncthreads();
        unsigned* dp = partial + (size_t)g * HWORDS + (lo >> 1);
        for (int i = t; i < HBINS / 2; i += 512) dp[i] = lds[i];
        __syncthreads();
    }
}

// ---------------- fused: per-chunk exclusive scan + degree reduce + norms ----
__global__ __launch_bounds__(256)
void degscan_kernel(const unsigned* __restrict__ partial,
                    unsigned char* __restrict__ offb,
                    float* __restrict__ ns, float* __restrict__ nd,
                    int* __restrict__ cnt_in) {
    int w = blockIdx.x * 256 + threadIdx.x;
    if (w >= HWORDS) return;
    unsigned o0 = 0, i0 = 0, o1 = 0, i1 = 0;
    for (int g = 0; g < HG; ++g) {
        unsigned v = partial[(size_t)g * HWORDS + w];
        unsigned char* ob = offb + (size_t)g * NNODES;
        ob[2 * w]     = (unsigned char)i0;     // exclusive running in-degree
        ob[2 * w + 1] = (unsigned char)i1;
        o0 += v & 0xffu;         i0 += (v >> 8) & 0xffu;
        o1 += (v >> 16) & 0xffu; i1 += v >> 24;
    }
    int n0 = 2 * w, n1 = 2 * w + 1;
    ns[n0] = rsqrtf((float)max((int)o0, 1));
    nd[n0] = rsqrtf((float)max((int)i0, 1));
    cnt_in[n0] = (int)i0;
    ns[n1] = rsqrtf((float)max((int)o1, 1));
    nd[n1] = rsqrtf((float)max((int)i1, 1));
    cnt_in[n1] = (int)i1;
}

// ---------------- 3-pass exclusive scan over cnt_in -> row_ptr --------------
__global__ __launch_bounds__(256)
void scanA_kernel(const int* __restrict__ cnt, int* __restrict__ pre,
                  int* __restrict__ bsum, int n) {
    __shared__ int tsum[256];
    int b = blockIdx.x, t = threadIdx.x;
    int base = b * SCAN_ELEMS + t * 4;
    int v[4]; int s = 0;
    #pragma unroll
    for (int k = 0; k < 4; ++k) { int idx = base + k; v[k] = (idx < n) ? cnt[idx] : 0; s += v[k]; }
    tsum[t] = s;
    __syncthreads();
    for (int off = 1; off < 256; off <<= 1) {
        int val = (t >= off) ? tsum[t - off] : 0;
        __syncthreads();
        tsum[t] += val;
        __syncthreads();
    }
    int run = (t == 0) ? 0 : tsum[t - 1];
    #pragma unroll
    for (int k = 0; k < 4; ++k) { int idx = base + k; if (idx < n) pre[idx] = run; run += v[k]; }
    if (t == 255) bsum[b] = tsum[255];
}

__global__ __launch_bounds__(128)
void scanB_kernel(int* __restrict__ bsum, int nb, int* __restrict__ row_ptr) {
    __shared__ int s[128];
    int t = threadIdx.x;
    int v = (t < nb) ? bsum[t] : 0;
    s[t] = v;
    __syncthreads();
    for (int off = 1; off < 128; off <<= 1) {
        int u = (t >= off) ? s[t - off] : 0;
        __syncthreads();
        s[t] += u;
        __syncthreads();
    }
    if (t < nb) bsum[t] = s[t] - v;           // exclusive block sums
    if (t == 0) row_ptr[NNODES] = NEDGES;
}

__global__ __launch_bounds__(256)
void scanC_kernel(int* __restrict__ pre, const int* __restrict__ bsum, int n) {
    int add = bsum[blockIdx.x];
    int base = blockIdx.x * SCAN_ELEMS + threadIdx.x;
    #pragma unroll
    for (int k = 0; k < 4; ++k) {
        int idx = base + k * 256;
        if (idx < n) pre[idx] += add;
    }
}

// ---------------- atomic-free bucket fill -----------------------------------
__global__ __launch_bounds__(512)
void fill_kernel(const int* __restrict__ src, const int* __restrict__ dst,
                 const int* __restrict__ row_ptr, const unsigned char* __restrict__ offb,
                 int* __restrict__ col) {
    __shared__ unsigned lcur[HBINS / 2];       // 12500 words, 2x16-bit counters
    const int g = blockIdx.x, t = threadIdx.x;
    const int e0 = g * HCHUNK;
    const unsigned char* ob = offb + (size_t)g * NNODES;
    for (int r = 0; r < HR; ++r) {
        const int lo = r * HBINS;
        for (int i = t; i < HBINS / 2; i += 512) lcur[i] = 0;
        __syncthreads();
        for (int i = t; i < HCHUNK; i += 512) {
            int d = dst[e0 + i];
            unsigned ud = (unsigned)(d - lo);
            if (ud < HBINS) {
                unsigned prev = atomicAdd(&lcur[ud >> 1], 1u << ((ud & 1) * 16));
                unsigned rank = (prev >> ((ud & 1) * 16)) & 0xffffu;
                int p = row_ptr[d] + (int)ob[d] + (int)rank;
                col[p] = src[e0 + i];
            }
        }
        __syncthreads();
    }
}

// ---------------- weight prep: W1 transpose+perm, b1 perm, v2 = W2@Wfc, c0 --
__global__ __launch_bounds__(256)
void prep_w_kernel(const float* __restrict__ W1, const float* __restrict__ b1,
                   _Float16* __restrict__ Wt1, float* __restrict__ b1p,
                   const float* __restrict__ W2, const float* __restrict__ Wfc,
                   const float* __restrict__ b2, const float* __restrict__ bfc,
                   float* __restrict__ v2p, float* __restrict__ c0) {
    int b = blockIdx.x, t = threadIdx.x;
    if (b < WPREP_BLOCKS) {
        int id = b * 256 + t;
        if (id < NF * NH) {                    // W1 -> Wt1[n][perm(k)] f16
            int k = id >> 7, n = id & 127;
            Wt1[(size_t)n * NF + (k & ~15) + pos16(k & 15)] = (_Float16)W1[id];
        } else if (id < NF * NH + NH) {
            int pos = id - NF * NH;
            int k = (pos & ~15) + ipos16(pos & 15);
            b1p[pos] = b1[k];
        }
    } else {
        // v2 = W2 @ Wfc (perm order), c0 = b2.Wfc + bfc
        if (t < 128) {
            float s = 0.f;
            #pragma unroll 16
            for (int j = 0; j < 128; ++j) s += W2[t * 128 + j] * Wfc[j];
            v2p[(t & ~15) + pos16(t & 15)] = s;
        } else if (t < 192) {
            int lane = t - 128;
            float c = b2[lane] * Wfc[lane] + b2[lane + 64] * Wfc[lane + 64];
            #pragma unroll
            for (int off = 32; off > 0; off >>= 1) c += __shfl_down(c, off);
            if (lane == 0) c0[0] = c + bfc[0];
        }
    }
}

// ---------------- fused GEMM1: C = (x @ W1) * ns, BK=64 DMA pipeline --------
// Stages 128-row x 64-f32 K-slabs (32 KB LDS -> 4 blocks/CU resident, single
// dispatch round for 782 blocks) via global_load_lds. XOR chunk-swizzle on the
// per-lane GLOBAL source + matching XOR on ds_read (rule 21). f32->f16 convert
// in-register after ds_read. ns applied in epilogue. B from L2-resident Wt1.
__global__ __launch_bounds__(256, 4)
void gemm1_kernel(const float* __restrict__ X, const _Float16* __restrict__ Wt,
                  const float* __restrict__ norm_s, _Float16* __restrict__ Cout,
                  int N) {
    __shared__ __align__(16) float As[128 * 64];    // one BK=64 slab (32 KB)
    const int tid = threadIdx.x;
    const int l = tid & 63, w = tid >> 6;
    const int wr = w >> 1, wc = w & 1;         // 2x2 wave grid, 64x64 per wave
    const int row0 = blockIdx.x * 128;

    // B fragment base: col = wc*64 + n*32 + (l&31), k-chunk (l>>5)*8 (perm layout)
    const _Float16* Bb = Wt + (size_t)(wc * 64 + (l & 31)) * NF + (l >> 5) * 8;
    const int ar = wr * 64 + (l & 31);
    const int swz = ar & 7;                    // (ar+32)&7 == ar&7
    const int g = l >> 5;
    const int lr = l >> 4, lc = l & 15;        // staging: 4 rows/instr, 16 chunks/row
    floatx16 acc[2][2] = {};

    for (int step = 0; step < 4; ++step) {
        // stage 128 rows x 64 f32: wave w covers rows [w*32, w*32+32), 8 DMAs
        #pragma unroll
        for (int i = 0; i < 8; ++i) {
            int R = w * 32 + i * 4;
            int r = R + lr;
            int grow = row0 + r;
            int srcc = lc ^ (r & 7);           // pre-swizzled source chunk
            if (grow < N)
                load_lds16(X + (size_t)grow * NF + step * 64 + srcc * 4,
                           &As[(size_t)R * 64]);
        }
        __syncthreads();
        #pragma unroll
        for (int kk = 0; kk < 4; ++kk) {
            int ca = kk * 4 + g;               // chunk with k = 16kk+4g+0..3
            int cb = ca + 2;                   // chunk with k = 16kk+4g+8..11
            float4 a0l = *(const float4*)&As[(size_t)ar * 64 + (ca ^ swz) * 4];
            float4 a0h = *(const float4*)&As[(size_t)ar * 64 + (cb ^ swz) * 4];
            float4 a1l = *(const float4*)&As[(size_t)(ar + 32) * 64 + (ca ^ swz) * 4];
            float4 a1h = *(const float4*)&As[(size_t)(ar + 32) * 64 + (cb ^ swz) * 4];
            half8v a0 = { (_Float16)a0l.x, (_Float16)a0l.y, (_Float16)a0l.z, (_Float16)a0l.w,
                          (_Float16)a0h.x, (_Float16)a0h.y, (_Float16)a0h.z, (_Float16)a0h.w };
            half8v a1 = { (_Float16)a1l.x, (_Float16)a1l.y, (_Float16)a1l.z, (_Float16)a1l.w,
                          (_Float16)a1h.x, (_Float16)a1h.y, (_Float16)a1h.z, (_Float16)a1h.w };
            const _Float16* bp = Bb + (step * 4 + kk) * 16;
            half8v b0 = *(const half8v*)bp;
            half8v b1 = *(const half8v*)(bp + (size_t)32 * NF);
            acc[0][0] = __builtin_amdgcn_mfma_f32_32x32x16_f16(a0, b0, acc[0][0], 0, 0, 0);
            acc[0][1] = __builtin_amdgcn_mfma_f32_32x32x16_f16(a0, b1, acc[0][1], 0, 0, 0);
            acc[1][0] = __builtin_amdgcn_mfma_f32_32x32x16_f16(a1, b0, acc[1][0], 0, 0, 0);
            acc[1][1] = __builtin_amdgcn_mfma_f32_32x32x16_f16(a1, b1, acc[1][1], 0, 0, 0);
        }
        __syncthreads();
    }

    // epilogue: D row = (r&3)+8*(r>>2)+4*(l>>5), col = l&31; scale by ns[row]
    const int cpos = pos16(l & 15);
    const int chi = ((l >> 4) & 1) << 4;
    #pragma unroll
    for (int m = 0; m < 2; ++m) {
        #pragma unroll
        for (int r = 0; r < 16; ++r) {
            int rloc = wr * 64 + m * 32 + (r & 3) + ((r >> 2) << 3) + ((l >> 5) << 2);
            int grow = row0 + rloc;
            if (grow < N) {
                float s = norm_s[grow];
                #pragma unroll
                for (int n = 0; n < 2; ++n) {
                    int colbase = wc * 64 + n * 32 + chi;
                    Cout[(size_t)grow * NH + colbase + cpos] = (_Float16)(acc[m][n][r] * s);
                }
            }
        }
    }
}

// ---------------- fused gather + layer-1 epilogue + z-dot, one wave/node ----
// z[w] = dot(relu(agg*nd + b1p)*ns, v2p); unroll-16, scalarized row_ptr
__global__ __launch_bounds__(512)
void gatherz_kernel(const _Float16* __restrict__ m, const int* __restrict__ row_ptr,
                    const int* __restrict__ col, const float* __restrict__ norm_d,
                    const float* __restrict__ norm_s, const float* __restrict__ b1p,
                    const float* __restrict__ v2p, float* __restrict__ z, int N) {
    int w = (blockIdx.x * 512 + threadIdx.x) >> 6;
    int lane = threadIdx.x & 63;
    if (w >= N) return;
    int beg = __builtin_amdgcn_readfirstlane(row_ptr[w]);
    int end = __builtin_amdgcn_readfirstlane(row_ptr[w + 1]);
    const unsigned* mu = (const unsigned*)m + lane;  // lane's column slot
    float ax = 0.f, ay = 0.f;
    int i = beg;
    for (; i + 15 < end; i += 16) {
        unsigned u[16];
        #pragma unroll
        for (int j = 0; j < 16; ++j) u[j] = mu[(size_t)col[i + j] * 64];
        #pragma unroll
        for (int j = 0; j < 16; ++j) { float2 v = h2f2(u[j]); ax += v.x; ay += v.y; }
    }
    for (; i + 3 < end; i += 4) {
        unsigned u[4];
        #pragma unroll
        for (int j = 0; j < 4; ++j) u[j] = mu[(size_t)col[i + j] * 64];
        #pragma unroll
        for (int j = 0; j < 4; ++j) { float2 v = h2f2(u[j]); ax += v.x; ay += v.y; }
    }
    for (; i < end; ++i) {
        float2 v = h2f2(mu[(size_t)col[i] * 64]);
        ax += v.x; ay += v.y;
    }
    float nd = norm_d[w], ns = norm_s[w];
    float2 bv = ((const float2*)b1p)[lane];
    float hx = fmaxf(fmaf(ax, nd, bv.x), 0.f) * ns;
    float hy = fmaxf(fmaf(ay, nd, bv.y), 0.f) * ns;
    float2 w2 = ((const float2*)v2p)[lane];
    float p = fmaf(hx, w2.x, hy * w2.y);
    #pragma unroll
    for (int off = 32; off > 0; off >>= 1) p += __shfl_down(p, off);
    if (lane == 0) z[w] = p;
}

// ---------------- scalar CSR sum: out[w] = nd*sum z[col] + c0 ---------------
__global__ __launch_bounds__(256)
void outsum_kernel(const float* __restrict__ z, const int* __restrict__ row_ptr,
                   const int* __restrict__ col, const float* __restrict__ norm_d,
                   const float* __restrict__ c0, float* __restrict__ out, int N) {
    int w = blockIdx.x * 256 + threadIdx.x;
    if (w >= N) return;
    int beg = row_ptr[w], end = row_ptr[w + 1];
    float s0 = 0.f, s1 = 0.f, s2 = 0.f, s3 = 0.f;
    int i = beg;
    for (; i + 3 < end; i += 4) {
        s0 += z[col[i]];     s1 += z[col[i + 1]];
        s2 += z[col[i + 2]]; s3 += z[col[i + 3]];
    }
    for (; i < end; ++i) s0 += z[col[i]];
    out[w] = norm_d[w] * ((s0 + s1) + (s2 + s3)) + c0[0];
}

extern "C" void kernel_launch(void* const* d_in, const int* in_sizes, int n_in,
                              void* d_out, int out_size, void* d_ws, size_t ws_size,
                              hipStream_t stream) {
    const float* x   = (const float*)d_in[0];
    const float* W1  = (const float*)d_in[1];
    const float* b1  = (const float*)d_in[2];
    const float* W2  = (const float*)d_in[3];
    const float* b2  = (const float*)d_in[4];
    const float* Wfc = (const float*)d_in[5];
    const float* bfc = (const float*)d_in[6];
    const int*   src = (const int*)d_in[7];
    const int*   dst = (const int*)d_in[8];
    float* out = (float*)d_out;

    const int N = NNODES, E = NEDGES;

    // workspace layout (all offsets 16B-aligned)
    char* p = (char*)d_ws;
    float*    norm_s = (float*)p;      p += (size_t)N * 4;
    float*    norm_d = (float*)p;      p += (size_t)N * 4;
    _Float16* bufA_h = (_Float16*)p;   p += (size_t)N * NH * 2;   // m1 (25.6 MB)
    _Float16* Wt1    = (_Float16*)p;   p += (size_t)NF * NH * 2;
    float*    b1p    = (float*)p;      p += NH * 4;
    float*    v2p    = (float*)p;      p += NH * 4;
    float*    c0     = (float*)p;      p += 16;
    float*    z      = (float*)p;      p += (size_t)N * 4;
    int*      cnt_in = (int*)p;        p += (size_t)N * 4;
    int*      row_ptr= (int*)p;        p += (size_t)(N + 1) * 4 + 12;  // keep 16B align
    int*      col    = (int*)p;        p += (size_t)E * 4;
    int*      bsum   = (int*)p;        p += 128 * 4;
    unsigned* partial= (unsigned*)p;   // HG * HWORDS * 4 = 40 MB
    // offb (20 MB) aliases bufA_h (25.6 MB): dead before gemm1 writes bufA_h.
    unsigned char* offb = (unsigned char*)bufA_h;

    // ---- CSR build + norms + weight prep (zero global atomics) ----
    hist_part_kernel<<<HG, 512, 0, stream>>>(src, dst, partial);
    degscan_kernel<<<(HWORDS + 255) / 256, 256, 0, stream>>>(partial, offb, norm_s, norm_d, cnt_in);
    scanA_kernel<<<SCAN_NBLK, 256, 0, stream>>>(cnt_in, row_ptr, bsum, N);
    scanB_kernel<<<1, 128, 0, stream>>>(bsum, SCAN_NBLK, row_ptr);
    scanC_kernel<<<SCAN_NBLK, 256, 0, stream>>>(row_ptr, bsum, N);
    fill_kernel<<<HG, 512, 0, stream>>>(src, dst, row_ptr, offb, col);
    prep_w_kernel<<<WPREP_BLOCKS + 1, 256, 0, stream>>>(W1, b1, Wt1, b1p,
                                                        W2, Wfc, b2, bfc, v2p, c0);

    // ---- layer 1 GEMM (convx fused, BK=64 pipeline): m1 = (x @ W1) * ns ----
    gemm1_kernel<<<(N + 127) / 128, 256, 0, stream>>>(x, Wt1, norm_s, bufA_h, N);
    // ---- fused: agg1 -> h -> z (layer 2 collapsed into v2 dot) ----
    gatherz_kernel<<<((size_t)N * 64 + 511) / 512, 512, 0, stream>>>(
        bufA_h, row_ptr, col, norm_d, norm_s, b1p, v2p, z, N);
    // ---- out[w] = nd * sum z[col] + c0 ----
    outsum_kernel<<<(N + 255) / 256, 256, 0, stream>>>(z, row_ptr, col, norm_d, c0, out, N);
}

// Round 15
// 198.786 us; speedup vs baseline: 1.4358x; 1.3124x over previous
//
#include <hip/hip_runtime.h>
#include <hip/hip_bf16.h>

#define NNODES 100000
#define NEDGES 1600000
#define NF 256
#define NH 128
#define SCAN_ELEMS 1024
#define SCAN_NBLK ((NNODES + SCAN_ELEMS - 1) / SCAN_ELEMS)   // 98

// LDS-privatized histogram / fill parameters
#define HG 200                     // workgroups (chunks)
#define HCHUNK (NEDGES / HG)       // 8000 edges per WG
#define HBINS 50000                // nodes per pass (100 KB LDS)
#define HR 2                       // passes (2 * 50000 = 100000)
#define HWORDS (NNODES / 2)        // 50000 packed words per partial slice

#define WPREP_BLOCKS 129           // (NF*NH + NH + 255)/256

typedef _Float16 half4v __attribute__((ext_vector_type(4)));
typedef _Float16 half8v __attribute__((ext_vector_type(8)));
typedef float floatx16 __attribute__((ext_vector_type(16)));

// k-permutation within each 16-block so MFMA f16 fragments (k = g*4 + (j&3) + 8*(j>>2))
// are 8 contiguous halves in storage. perm: [0,1,2,3, 8,9,10,11, 4,5,6,7, 12,13,14,15]
__device__ __forceinline__ int pos16(int k) {        // logical k (0..15) -> storage pos
    return (((k >> 2) & 1) << 3) + (k & 3) + (((k >> 3) & 1) << 2);
}
__device__ __forceinline__ int ipos16(int p) {       // storage pos -> logical k
    int g = (p >> 3) & 1, j = p & 7;
    return g * 4 + (j & 3) + ((j >> 2) << 3);
}

__device__ __forceinline__ float2 h2f2(unsigned u) {
    union { unsigned u; _Float16 h[2]; } c; c.u = u;
    return make_float2((float)c.h[0], (float)c.h[1]);
}

// async global->LDS DMA, 16 B per lane; LDS dest = wave base + lane*16 (linear)
__device__ __forceinline__ void load_lds16(const void* g, void* l) {
    __builtin_amdgcn_global_load_lds(
        (const __attribute__((address_space(1))) void*)g,
        (__attribute__((address_space(3))) void*)l, 16, 0, 0);
}

// ---------------- LDS-privatized degree histogram (2 passes) ----------------
__global__ __launch_bounds__(512)
void hist_part_kernel(const int* __restrict__ src, const int* __restrict__ dst,
                      unsigned* __restrict__ partial) {
    __shared__ unsigned lds[HBINS / 2];        // 25000 words = 100 KB
    const int g = blockIdx.x, t = threadIdx.x;
    const int e0 = g * HCHUNK;
    for (int r = 0; r < HR; ++r) {
        const int lo = r * HBINS;
        for (int i = t; i < HBINS / 2; i += 512) lds[i] = 0;
        __syncthreads();
        for (int i = t; i < HCHUNK; i += 512) {
            unsigned us = (unsigned)(src[e0 + i] - lo);
            if (us < HBINS) atomicAdd(&lds[us >> 1], 1u << ((us & 1) * 16));
            unsigned ud = (unsigned)(dst[e0 + i] - lo);
            if (ud < HBINS) atomicAdd(&lds[ud >> 1], 1u << ((ud & 1) * 16 + 8));
        }
        __syncthreads();
        unsigned* dp = partial + (size_t)g * HWORDS + (lo >> 1);
        for (int i = t; i < HBINS / 2; i += 512) dp[i] = lds[i];
        __syncthreads();
    }
}

// ---------------- fused: per-chunk exclusive scan + degree reduce + norms ----
// unroll-8: 8 strided L3 reads in flight; u16-packed offb store
__global__ __launch_bounds__(256)
void degscan_kernel(const unsigned* __restrict__ partial,
                    unsigned char* __restrict__ offb,
                    float* __restrict__ ns, float* __restrict__ nd,
                    int* __restrict__ cnt_in) {
    int w = blockIdx.x * 256 + threadIdx.x;
    if (w >= HWORDS) return;
    unsigned o0 = 0, i0 = 0, o1 = 0, i1 = 0;
    for (int g0 = 0; g0 < HG; g0 += 8) {
        unsigned v[8];
        #pragma unroll
        for (int j = 0; j < 8; ++j) v[j] = partial[(size_t)(g0 + j) * HWORDS + w];
        #pragma unroll
        for (int j = 0; j < 8; ++j) {
            *(unsigned short*)(offb + (size_t)(g0 + j) * NNODES + 2 * w) =
                (unsigned short)((i0 & 0xffu) | ((i1 & 0xffu) << 8));
            o0 += v[j] & 0xffu;         i0 += (v[j] >> 8) & 0xffu;
            o1 += (v[j] >> 16) & 0xffu; i1 += v[j] >> 24;
        }
    }
    int n0 = 2 * w, n1 = 2 * w + 1;
    ns[n0] = rsqrtf((float)max((int)o0, 1));
    nd[n0] = rsqrtf((float)max((int)i0, 1));
    cnt_in[n0] = (int)i0;
    ns[n1] = rsqrtf((float)max((int)o1, 1));
    nd[n1] = rsqrtf((float)max((int)i1, 1));
    cnt_in[n1] = (int)i1;
}

// ---------------- 3-pass exclusive scan over cnt_in -> row_ptr --------------
__global__ __launch_bounds__(256)
void scanA_kernel(const int* __restrict__ cnt, int* __restrict__ pre,
                  int* __restrict__ bsum, int n) {
    __shared__ int tsum[256];
    int b = blockIdx.x, t = threadIdx.x;
    int base = b * SCAN_ELEMS + t * 4;
    int v[4]; int s = 0;
    #pragma unroll
    for (int k = 0; k < 4; ++k) { int idx = base + k; v[k] = (idx < n) ? cnt[idx] : 0; s += v[k]; }
    tsum[t] = s;
    __syncthreads();
    for (int off = 1; off < 256; off <<= 1) {
        int val = (t >= off) ? tsum[t - off] : 0;
        __syncthreads();
        tsum[t] += val;
        __syncthreads();
    }
    int run = (t == 0) ? 0 : tsum[t - 1];
    #pragma unroll
    for (int k = 0; k < 4; ++k) { int idx = base + k; if (idx < n) pre[idx] = run; run += v[k]; }
    if (t == 255) bsum[b] = tsum[255];
}

__global__ __launch_bounds__(128)
void scanB_kernel(int* __restrict__ bsum, int nb, int* __restrict__ row_ptr) {
    __shared__ int s[128];
    int t = threadIdx.x;
    int v = (t < nb) ? bsum[t] : 0;
    s[t] = v;
    __syncthreads();
    for (int off = 1; off < 128; off <<= 1) {
        int u = (t >= off) ? s[t - off] : 0;
        __syncthreads();
        s[t] += u;
        __syncthreads();
    }
    if (t < nb) bsum[t] = s[t] - v;           // exclusive block sums
    if (t == 0) row_ptr[NNODES] = NEDGES;
}

__global__ __launch_bounds__(256)
void scanC_kernel(int* __restrict__ pre, const int* __restrict__ bsum, int n) {
    int add = bsum[blockIdx.x];
    int base = blockIdx.x * SCAN_ELEMS + threadIdx.x;
    #pragma unroll
    for (int k = 0; k < 4; ++k) {
        int idx = base + k * 256;
        if (idx < n) pre[idx] += add;
    }
}

// ---------------- atomic-free bucket fill (2 passes) ------------------------
__global__ __launch_bounds__(512)
void fill_kernel(const int* __restrict__ src, const int* __restrict__ dst,
                 const int* __restrict__ row_ptr, const unsigned char* __restrict__ offb,
                 int* __restrict__ col) {
    __shared__ unsigned lcur[HBINS / 2];       // 25000 words, 2x16-bit counters
    const int g = blockIdx.x, t = threadIdx.x;
    const int e0 = g * HCHUNK;
    const unsigned char* ob = offb + (size_t)g * NNODES;
    for (int r = 0; r < HR; ++r) {
        const int lo = r * HBINS;
        for (int i = t; i < HBINS / 2; i += 512) lcur[i] = 0;
        __syncthreads();
        for (int i = t; i < HCHUNK; i += 512) {
            int d = dst[e0 + i];
            unsigned ud = (unsigned)(d - lo);
            if (ud < HBINS) {
                unsigned prev = atomicAdd(&lcur[ud >> 1], 1u << ((ud & 1) * 16));
                unsigned rank = (prev >> ((ud & 1) * 16)) & 0xffffu;
                int p = row_ptr[d] + (int)ob[d] + (int)rank;
                col[p] = src[e0 + i];
            }
        }
        __syncthreads();
    }
}

// ---------------- weight prep: W1 transpose+perm, b1 perm, v2 = W2@Wfc, c0 --
__global__ __launch_bounds__(256)
void prep_w_kernel(const float* __restrict__ W1, const float* __restrict__ b1,
                   _Float16* __restrict__ Wt1, float* __restrict__ b1p,
                   const float* __restrict__ W2, const float* __restrict__ Wfc,
                   const float* __restrict__ b2, const float* __restrict__ bfc,
                   float* __restrict__ v2p, float* __restrict__ c0) {
    int b = blockIdx.x, t = threadIdx.x;
    if (b < WPREP_BLOCKS) {
        int id = b * 256 + t;
        if (id < NF * NH) {                    // W1 -> Wt1[n][perm(k)] f16
            int k = id >> 7, n = id & 127;
            Wt1[(size_t)n * NF + (k & ~15) + pos16(k & 15)] = (_Float16)W1[id];
        } else if (id < NF * NH + NH) {
            int pos = id - NF * NH;
            int k = (pos & ~15) + ipos16(pos & 15);
            b1p[pos] = b1[k];
        }
    } else {
        // v2 = W2 @ Wfc (perm order), c0 = b2.Wfc + bfc
        if (t < 128) {
            float s = 0.f;
            #pragma unroll 16
            for (int j = 0; j < 128; ++j) s += W2[t * 128 + j] * Wfc[j];
            v2p[(t & ~15) + pos16(t & 15)] = s;
        } else if (t < 192) {
            int lane = t - 128;
            float c = b2[lane] * Wfc[lane] + b2[lane + 64] * Wfc[lane + 64];
            #pragma unroll
            for (int off = 32; off > 0; off >>= 1) c += __shfl_down(c, off);
            if (lane == 0) c0[0] = c + bfc[0];
        }
    }
}

// ---------------- fused GEMM1: C = (x @ W1) * ns, BK=64 DMA pipeline --------
// De-convoyed: each block starts its K-step loop at step (blockIdx.x & 3) and
// wraps (K-accumulation commutes), so resident blocks' DMA bursts interleave
// instead of phasing in lockstep. 32 KB LDS -> 4 blocks/CU, all 782 resident.
__global__ __launch_bounds__(256, 4)
void gemm1_kernel(const float* __restrict__ X, const _Float16* __restrict__ Wt,
                  const float* __restrict__ norm_s, _Float16* __restrict__ Cout,
                  int N) {
    __shared__ __align__(16) float As[128 * 64];    // one BK=64 slab (32 KB)
    const int tid = threadIdx.x;
    const int l = tid & 63, w = tid >> 6;
    const int wr = w >> 1, wc = w & 1;         // 2x2 wave grid, 64x64 per wave
    const int row0 = blockIdx.x * 128;
    const int s0 = blockIdx.x & 3;             // de-convoy phase offset

    // B fragment base: col = wc*64 + n*32 + (l&31), k-chunk (l>>5)*8 (perm layout)
    const _Float16* Bb = Wt + (size_t)(wc * 64 + (l & 31)) * NF + (l >> 5) * 8;
    const int ar = wr * 64 + (l & 31);
    const int swz = ar & 7;                    // (ar+32)&7 == ar&7
    const int g = l >> 5;
    const int lr = l >> 4, lc = l & 15;        // staging: 4 rows/instr, 16 chunks/row
    floatx16 acc[2][2] = {};

    for (int ii = 0; ii < 4; ++ii) {
        const int step = (s0 + ii) & 3;
        // stage 128 rows x 64 f32: wave w covers rows [w*32, w*32+32), 8 DMAs
        #pragma unroll
        for (int i = 0; i < 8; ++i) {
            int R = w * 32 + i * 4;
            int r = R + lr;
            int grow = row0 + r;
            int srcc = lc ^ (r & 7);           // pre-swizzled source chunk
            if (grow < N)
                load_lds16(X + (size_t)grow * NF + step * 64 + srcc * 4,
                           &As[(size_t)R * 64]);
        }
        __syncthreads();
        #pragma unroll
        for (int kk = 0; kk < 4; ++kk) {
            int ca = kk * 4 + g;               // chunk with k = 16kk+4g+0..3
            int cb = ca + 2;                   // chunk with k = 16kk+4g+8..11
            float4 a0l = *(const float4*)&As[(size_t)ar * 64 + (ca ^ swz) * 4];
            float4 a0h = *(const float4*)&As[(size_t)ar * 64 + (cb ^ swz) * 4];
            float4 a1l = *(const float4*)&As[(size_t)(ar + 32) * 64 + (ca ^ swz) * 4];
            float4 a1h = *(const float4*)&As[(size_t)(ar + 32) * 64 + (cb ^ swz) * 4];
            half8v a0 = { (_Float16)a0l.x, (_Float16)a0l.y, (_Float16)a0l.z, (_Float16)a0l.w,
                          (_Float16)a0h.x, (_Float16)a0h.y, (_Float16)a0h.z, (_Float16)a0h.w };
            half8v a1 = { (_Float16)a1l.x, (_Float16)a1l.y, (_Float16)a1l.z, (_Float16)a1l.w,
                          (_Float16)a1h.x, (_Float16)a1h.y, (_Float16)a1h.z, (_Float16)a1h.w };
            const _Float16* bp = Bb + (step * 4 + kk) * 16;
            half8v b0 = *(const half8v*)bp;
            half8v b1 = *(const half8v*)(bp + (size_t)32 * NF);
            acc[0][0] = __builtin_amdgcn_mfma_f32_32x32x16_f16(a0, b0, acc[0][0], 0, 0, 0);
            acc[0][1] = __builtin_amdgcn_mfma_f32_32x32x16_f16(a0, b1, acc[0][1], 0, 0, 0);
            acc[1][0] = __builtin_amdgcn_mfma_f32_32x32x16_f16(a1, b0, acc[1][0], 0, 0, 0);
            acc[1][1] = __builtin_amdgcn_mfma_f32_32x32x16_f16(a1, b1, acc[1][1], 0, 0, 0);
        }
        __syncthreads();
    }

    // epilogue: D row = (r&3)+8*(r>>2)+4*(l>>5), col = l&31; scale by ns[row]
    const int cpos = pos16(l & 15);
    const int chi = ((l >> 4) & 1) << 4;
    #pragma unroll
    for (int m = 0; m < 2; ++m) {
        #pragma unroll
        for (int r = 0; r < 16; ++r) {
            int rloc = wr * 64 + m * 32 + (r & 3) + ((r >> 2) << 3) + ((l >> 5) << 2);
            int grow = row0 + rloc;
            if (grow < N) {
                float s = norm_s[grow];
                #pragma unroll
                for (int n = 0; n < 2; ++n) {
                    int colbase = wc * 64 + n * 32 + chi;
                    Cout[(size_t)grow * NH + colbase + cpos] = (_Float16)(acc[m][n][r] * s);
                }
            }
        }
    }
}

// ---------------- fused gather + layer-1 epilogue + z-dot, one wave/node ----
// z[w] = dot(relu(agg*nd + b1p)*ns, v2p); unroll-16, scalarized row_ptr
__global__ __launch_bounds__(512)
void gatherz_kernel(const _Float16* __restrict__ m, const int* __restrict__ row_ptr,
                    const int* __restrict__ col, const float* __restrict__ norm_d,
                    const float* __restrict__ norm_s, const float* __restrict__ b1p,
                    const float* __restrict__ v2p, float* __restrict__ z, int N) {
    int w = (blockIdx.x * 512 + threadIdx.x) >> 6;
    int lane = threadIdx.x & 63;
    if (w >= N) return;
    int beg = __builtin_amdgcn_readfirstlane(row_ptr[w]);
    int end = __builtin_amdgcn_readfirstlane(row_ptr[w + 1]);
    const unsigned* mu = (const unsigned*)m + lane;  // lane's column slot
    float ax = 0.f, ay = 0.f;
    int i = beg;
    for (; i + 15 < end; i += 16) {
        unsigned u[16];
        #pragma unroll
        for (int j = 0; j < 16; ++j) u[j] = mu[(size_t)col[i + j] * 64];
        #pragma unroll
        for (int j = 0; j < 16; ++j) { float2 v = h2f2(u[j]); ax += v.x; ay += v.y; }
    }
    for (; i + 3 < end; i += 4) {
        unsigned u[4];
        #pragma unroll
        for (int j = 0; j < 4; ++j) u[j] = mu[(size_t)col[i + j] * 64];
        #pragma unroll
        for (int j = 0; j < 4; ++j) { float2 v = h2f2(u[j]); ax += v.x; ay += v.y; }
    }
    for (; i < end; ++i) {
        float2 v = h2f2(mu[(size_t)col[i] * 64]);
        ax += v.x; ay += v.y;
    }
    float nd = norm_d[w], ns = norm_s[w];
    float2 bv = ((const float2*)b1p)[lane];
    float hx = fmaxf(fmaf(ax, nd, bv.x), 0.f) * ns;
    float hy = fmaxf(fmaf(ay, nd, bv.y), 0.f) * ns;
    float2 w2 = ((const float2*)v2p)[lane];
    float p = fmaf(hx, w2.x, hy * w2.y);
    #pragma unroll
    for (int off = 32; off > 0; off >>= 1) p += __shfl_down(p, off);
    if (lane == 0) z[w] = p;
}

// ---------------- scalar CSR sum: out[w] = nd*sum z[col] + c0 ---------------
__global__ __launch_bounds__(256)
void outsum_kernel(const float* __restrict__ z, const int* __restrict__ row_ptr,
                   const int* __restrict__ col, const float* __restrict__ norm_d,
                   const float* __restrict__ c0, float* __restrict__ out, int N) {
    int w = blockIdx.x * 256 + threadIdx.x;
    if (w >= N) return;
    int beg = row_ptr[w], end = row_ptr[w + 1];
    float s0 = 0.f, s1 = 0.f, s2 = 0.f, s3 = 0.f;
    int i = beg;
    for (; i + 3 < end; i += 4) {
        s0 += z[col[i]];     s1 += z[col[i + 1]];
        s2 += z[col[i + 2]]; s3 += z[col[i + 3]];
    }
    for (; i < end; ++i) s0 += z[col[i]];
    out[w] = norm_d[w] * ((s0 + s1) + (s2 + s3)) + c0[0];
}

extern "C" void kernel_launch(void* const* d_in, const int* in_sizes, int n_in,
                              void* d_out, int out_size, void* d_ws, size_t ws_size,
                              hipStream_t stream) {
    const float* x   = (const float*)d_in[0];
    const float* W1  = (const float*)d_in[1];
    const float* b1  = (const float*)d_in[2];
    const float* W2  = (const float*)d_in[3];
    const float* b2  = (const float*)d_in[4];
    const float* Wfc = (const float*)d_in[5];
    const float* bfc = (const float*)d_in[6];
    const int*   src = (const int*)d_in[7];
    const int*   dst = (const int*)d_in[8];
    float* out = (float*)d_out;

    const int N = NNODES, E = NEDGES;

    // workspace layout (all offsets 16B-aligned)
    char* p = (char*)d_ws;
    float*    norm_s = (float*)p;      p += (size_t)N * 4;
    float*    norm_d = (float*)p;      p += (size_t)N * 4;
    _Float16* bufA_h = (_Float16*)p;   p += (size_t)N * NH * 2;   // m1 (25.6 MB)
    _Float16* Wt1    = (_Float16*)p;   p += (size_t)NF * NH * 2;
    float*    b1p    = (float*)p;      p += NH * 4;
    float*    v2p    = (float*)p;      p += NH * 4;
    float*    c0     = (float*)p;      p += 16;
    float*    z      = (float*)p;      p += (size_t)N * 4;
    int*      cnt_in = (int*)p;        p += (size_t)N * 4;
    int*      row_ptr= (int*)p;        p += (size_t)(N + 1) * 4 + 12;  // keep 16B align
    int*      col    = (int*)p;        p += (size_t)E * 4;
    int*      bsum   = (int*)p;        p += 128 * 4;
    unsigned* partial= (unsigned*)p;   // HG * HWORDS * 4 = 40 MB
    // offb (20 MB) aliases bufA_h (25.6 MB): dead before gemm1 writes bufA_h.
    unsigned char* offb = (unsigned char*)bufA_h;

    // ---- CSR build + norms + weight prep (zero global atomics) ----
    hist_part_kernel<<<HG, 512, 0, stream>>>(src, dst, partial);
    degscan_kernel<<<(HWORDS + 255) / 256, 256, 0, stream>>>(partial, offb, norm_s, norm_d, cnt_in);
    scanA_kernel<<<SCAN_NBLK, 256, 0, stream>>>(cnt_in, row_ptr, bsum, N);
    scanB_kernel<<<1, 128, 0, stream>>>(bsum, SCAN_NBLK, row_ptr);
    scanC_kernel<<<SCAN_NBLK, 256, 0, stream>>>(row_ptr, bsum, N);
    fill_kernel<<<HG, 512, 0, stream>>>(src, dst, row_ptr, offb, col);
    prep_w_kernel<<<WPREP_BLOCKS + 1, 256, 0, stream>>>(W1, b1, Wt1, b1p,
                                                        W2, Wfc, b2, bfc, v2p, c0);

    // ---- layer 1 GEMM (convx fused, de-convoyed BK=64): m1 = (x @ W1) * ns ----
    gemm1_kernel<<<(N + 127) / 128, 256, 0, stream>>>(x, Wt1, norm_s, bufA_h, N);
    // ---- fused: agg1 -> h -> z (layer 2 collapsed into v2 dot) ----
    gatherz_kernel<<<((size_t)N * 64 + 511) / 512, 512, 0, stream>>>(
        bufA_h, row_ptr, col, norm_d, norm_s, b1p, v2p, z, N);
    // ---- out[w] = nd * sum z[col] + c0 ----
    outsum_kernel<<<(N + 255) / 256, 256, 0, stream>>>(z, row_ptr, col, norm_d, c0, out, N);
}

// Round 16
// 197.312 us; speedup vs baseline: 1.4465x; 1.0075x over previous
//
#include <hip/hip_runtime.h>
#include <hip/hip_bf16.h>

#define NNODES 100000
#define NEDGES 1600000
#define NF 256
#define NH 128
#define SCAN_ELEMS 1024
#define SCAN_NBLK ((NNODES + SCAN_ELEMS - 1) / SCAN_ELEMS)   // 98

// LDS-privatized histogram / fill parameters
#define HG 200                     // workgroups (chunks)
#define HCHUNK (NEDGES / HG)       // 8000 edges per WG
#define HBINS 50000                // nodes per pass (100 KB LDS)
#define HR 2                       // passes (2 * 50000 = 100000)
#define HWORDS (NNODES / 2)        // 50000 packed words per partial slice

#define WPREP_BLOCKS 129           // (NF*NH + NH + 255)/256

typedef _Float16 half4v __attribute__((ext_vector_type(4)));
typedef _Float16 half8v __attribute__((ext_vector_type(8)));
typedef float floatx16 __attribute__((ext_vector_type(16)));

// k-permutation within each 16-block so MFMA f16 fragments (k = g*4 + (j&3) + 8*(j>>2))
// are 8 contiguous halves in storage. perm: [0,1,2,3, 8,9,10,11, 4,5,6,7, 12,13,14,15]
__device__ __forceinline__ int pos16(int k) {        // logical k (0..15) -> storage pos
    return (((k >> 2) & 1) << 3) + (k & 3) + (((k >> 3) & 1) << 2);
}
__device__ __forceinline__ int ipos16(int p) {       // storage pos -> logical k
    int g = (p >> 3) & 1, j = p & 7;
    return g * 4 + (j & 3) + ((j >> 2) << 3);
}

__device__ __forceinline__ float2 h2f2(unsigned u) {
    union { unsigned u; _Float16 h[2]; } c; c.u = u;
    return make_float2((float)c.h[0], (float)c.h[1]);
}

// async global->LDS DMA, 16 B per lane; LDS dest = wave base + lane*16 (linear)
__device__ __forceinline__ void load_lds16(const void* g, void* l) {
    __builtin_amdgcn_global_load_lds(
        (const __attribute__((address_space(1))) void*)g,
        (__attribute__((address_space(3))) void*)l, 16, 0, 0);
}

// ---------------- LDS-privatized degree histogram (2 passes) ----------------
__global__ __launch_bounds__(512)
void hist_part_kernel(const int* __restrict__ src, const int* __restrict__ dst,
                      unsigned* __restrict__ partial) {
    __shared__ unsigned lds[HBINS / 2];        // 25000 words = 100 KB
    const int g = blockIdx.x, t = threadIdx.x;
    const int e0 = g * HCHUNK;
    for (int r = 0; r < HR; ++r) {
        const int lo = r * HBINS;
        for (int i = t; i < HBINS / 2; i += 512) lds[i] = 0;
        __syncthreads();
        for (int i = t; i < HCHUNK; i += 512) {
            unsigned us = (unsigned)(src[e0 + i] - lo);
            if (us < HBINS) atomicAdd(&lds[us >> 1], 1u << ((us & 1) * 16));
            unsigned ud = (unsigned)(dst[e0 + i] - lo);
            if (ud < HBINS) atomicAdd(&lds[ud >> 1], 1u << ((ud & 1) * 16 + 8));
        }
        __syncthreads();
        unsigned* dp = partial + (size_t)g * HWORDS + (lo >> 1);
        for (int i = t; i < HBINS / 2; i += 512) dp[i] = lds[i];
        __syncthreads();
    }
}

// ---------------- fused: per-chunk exclusive scan + degree reduce + norms ----
// unroll-8: 8 strided L3 reads in flight; u16-packed offb store
__global__ __launch_bounds__(256)
void degscan_kernel(const unsigned* __restrict__ partial,
                    unsigned char* __restrict__ offb,
                    float* __restrict__ ns, float* __restrict__ nd,
                    int* __restrict__ cnt_in) {
    int w = blockIdx.x * 256 + threadIdx.x;
    if (w >= HWORDS) return;
    unsigned o0 = 0, i0 = 0, o1 = 0, i1 = 0;
    for (int g0 = 0; g0 < HG; g0 += 8) {
        unsigned v[8];
        #pragma unroll
        for (int j = 0; j < 8; ++j) v[j] = partial[(size_t)(g0 + j) * HWORDS + w];
        #pragma unroll
        for (int j = 0; j < 8; ++j) {
            *(unsigned short*)(offb + (size_t)(g0 + j) * NNODES + 2 * w) =
                (unsigned short)((i0 & 0xffu) | ((i1 & 0xffu) << 8));
            o0 += v[j] & 0xffu;         i0 += (v[j] >> 8) & 0xffu;
            o1 += (v[j] >> 16) & 0xffu; i1 += v[j] >> 24;
        }
    }
    int n0 = 2 * w, n1 = 2 * w + 1;
    ns[n0] = rsqrtf((float)max((int)o0, 1));
    nd[n0] = rsqrtf((float)max((int)i0, 1));
    cnt_in[n0] = (int)i0;
    ns[n1] = rsqrtf((float)max((int)o1, 1));
    nd[n1] = rsqrtf((float)max((int)i1, 1));
    cnt_in[n1] = (int)i1;
}

// ---------------- 3-pass exclusive scan over cnt_in -> row_ptr --------------
__global__ __launch_bounds__(256)
void scanA_kernel(const int* __restrict__ cnt, int* __restrict__ pre,
                  int* __restrict__ bsum, int n) {
    __shared__ int tsum[256];
    int b = blockIdx.x, t = threadIdx.x;
    int base = b * SCAN_ELEMS + t * 4;
    int v[4]; int s = 0;
    #pragma unroll
    for (int k = 0; k < 4; ++k) { int idx = base + k; v[k] = (idx < n) ? cnt[idx] : 0; s += v[k]; }
    tsum[t] = s;
    __syncthreads();
    for (int off = 1; off < 256; off <<= 1) {
        int val = (t >= off) ? tsum[t - off] : 0;
        __syncthreads();
        tsum[t] += val;
        __syncthreads();
    }
    int run = (t == 0) ? 0 : tsum[t - 1];
    #pragma unroll
    for (int k = 0; k < 4; ++k) { int idx = base + k; if (idx < n) pre[idx] = run; run += v[k]; }
    if (t == 255) bsum[b] = tsum[255];
}

__global__ __launch_bounds__(128)
void scanB_kernel(int* __restrict__ bsum, int nb, int* __restrict__ row_ptr) {
    __shared__ int s[128];
    int t = threadIdx.x;
    int v = (t < nb) ? bsum[t] : 0;
    s[t] = v;
    __syncthreads();
    for (int off = 1; off < 128; off <<= 1) {
        int u = (t >= off) ? s[t - off] : 0;
        __syncthreads();
        s[t] += u;
        __syncthreads();
    }
    if (t < nb) bsum[t] = s[t] - v;           // exclusive block sums
    if (t == 0) row_ptr[NNODES] = NEDGES;
}

__global__ __launch_bounds__(256)
void scanC_kernel(int* __restrict__ pre, const int* __restrict__ bsum, int n) {
    int add = bsum[blockIdx.x];
    int base = blockIdx.x * SCAN_ELEMS + threadIdx.x;
    #pragma unroll
    for (int k = 0; k < 4; ++k) {
        int idx = base + k * 256;
        if (idx < n) pre[idx] += add;
    }
}

// ---------------- atomic-free bucket fill (2 passes) ------------------------
__global__ __launch_bounds__(512)
void fill_kernel(const int* __restrict__ src, const int* __restrict__ dst,
                 const int* __restrict__ row_ptr, const unsigned char* __restrict__ offb,
                 int* __restrict__ col) {
    __shared__ unsigned lcur[HBINS / 2];       // 25000 words, 2x16-bit counters
    const int g = blockIdx.x, t = threadIdx.x;
    const int e0 = g * HCHUNK;
    const unsigned char* ob = offb + (size_t)g * NNODES;
    for (int r = 0; r < HR; ++r) {
        const int lo = r * HBINS;
        for (int i = t; i < HBINS / 2; i += 512) lcur[i] = 0;
        __syncthreads();
        for (int i = t; i < HCHUNK; i += 512) {
            int d = dst[e0 + i];
            unsigned ud = (unsigned)(d - lo);
            if (ud < HBINS) {
                unsigned prev = atomicAdd(&lcur[ud >> 1], 1u << ((ud & 1) * 16));
                unsigned rank = (prev >> ((ud & 1) * 16)) & 0xffffu;
                int p = row_ptr[d] + (int)ob[d] + (int)rank;
                col[p] = src[e0 + i];
            }
        }
        __syncthreads();
    }
}

// ---------------- weight prep: W1 transpose+perm, b1 perm, v2 = W2@Wfc, c0 --
__global__ __launch_bounds__(256)
void prep_w_kernel(const float* __restrict__ W1, const float* __restrict__ b1,
                   _Float16* __restrict__ Wt1, float* __restrict__ b1p,
                   const float* __restrict__ W2, const float* __restrict__ Wfc,
                   const float* __restrict__ b2, const float* __restrict__ bfc,
                   float* __restrict__ v2p, float* __restrict__ c0) {
    int b = blockIdx.x, t = threadIdx.x;
    if (b < WPREP_BLOCKS) {
        int id = b * 256 + t;
        if (id < NF * NH) {                    // W1 -> Wt1[n][perm(k)] f16
            int k = id >> 7, n = id & 127;
            Wt1[(size_t)n * NF + (k & ~15) + pos16(k & 15)] = (_Float16)W1[id];
        } else if (id < NF * NH + NH) {
            int pos = id - NF * NH;
            int k = (pos & ~15) + ipos16(pos & 15);
            b1p[pos] = b1[k];
        }
    } else {
        // v2 = W2 @ Wfc (perm order), c0 = b2.Wfc + bfc
        if (t < 128) {
            float s = 0.f;
            #pragma unroll 16
            for (int j = 0; j < 128; ++j) s += W2[t * 128 + j] * Wfc[j];
            v2p[(t & ~15) + pos16(t & 15)] = s;
        } else if (t < 192) {
            int lane = t - 128;
            float c = b2[lane] * Wfc[lane] + b2[lane + 64] * Wfc[lane + 64];
            #pragma unroll
            for (int off = 32; off > 0; off >>= 1) c += __shfl_down(c, off);
            if (lane == 0) c0[0] = c + bfc[0];
        }
    }
}

// ---------------- fused GEMM1: C = (x @ W1) * ns, BK=32 dbuf + counted vmcnt -
// Double-buffered 16 KB slabs (32 KB LDS total -> 4 blocks/CU). Each step
// issues next slab's 4 DMAs, then waits vmcnt(4) (COUNTED: the 4 new DMAs stay
// in flight across the barrier) + raw s_barrier (no implicit drain). Rows are
// clamped (not predicated) so every wave issues exactly 4 DMAs -> uniform
// vmcnt. sched_barrier(0) + "memory" clobber pin ordering (no B-load hoisting
// above the waitcnt). XOR chunk-swizzle on global source + matching ds_read.
__global__ __launch_bounds__(256, 4)
void gemm1_kernel(const float* __restrict__ X, const _Float16* __restrict__ Wt,
                  const float* __restrict__ norm_s, _Float16* __restrict__ Cout,
                  int N) {
    __shared__ __align__(16) float As[2][128 * 32];   // 2 x 16 KB
    const int tid = threadIdx.x;
    const int l = tid & 63, w = tid >> 6;
    const int wr = w >> 1, wc = w & 1;         // 2x2 wave grid, 64x64 per wave
    const int row0 = blockIdx.x * 128;

    const _Float16* Bb = Wt + (size_t)(wc * 64 + (l & 31)) * NF + (l >> 5) * 8;
    const int ar = wr * 64 + (l & 31);
    const int swz = ar & 7;                    // (ar+32)&7 == ar&7
    const int g = l >> 5;
    const int lr = l >> 3, lc = l & 7;         // staging: 8 rows/DMA, 8 chunks/row
    floatx16 acc[2][2] = {};

    // prologue: stage slab 0 into buf 0 (4 DMAs, rows clamped)
    #pragma unroll
    for (int i = 0; i < 4; ++i) {
        int R = w * 32 + i * 8;
        int r = R + lr;
        int grow = min(row0 + r, N - 1);
        int srcc = lc ^ (r & 7);
        load_lds16(X + (size_t)grow * NF + srcc * 4, &As[0][R * 32]);
    }

    for (int t = 0; t < 8; ++t) {
        const int cur = t & 1;
        if (t < 7) {
            #pragma unroll
            for (int i = 0; i < 4; ++i) {
                int R = w * 32 + i * 8;
                int r = R + lr;
                int grow = min(row0 + r, N - 1);
                int srcc = lc ^ (r & 7);
                load_lds16(X + (size_t)grow * NF + (t + 1) * 32 + srcc * 4,
                           &As[cur ^ 1][R * 32]);
            }
            __builtin_amdgcn_sched_barrier(0);
            asm volatile("s_waitcnt vmcnt(4)" ::: "memory");   // slab t done; t+1 in flight
            __builtin_amdgcn_sched_barrier(0);
        } else {
            __builtin_amdgcn_sched_barrier(0);
            asm volatile("s_waitcnt vmcnt(0)" ::: "memory");
            __builtin_amdgcn_sched_barrier(0);
        }
        __builtin_amdgcn_s_barrier();          // raw: no implicit vmcnt(0) drain
        #pragma unroll
        for (int kk = 0; kk < 2; ++kk) {
            int ca = kk * 4 + g;               // chunk with k = 16kk+4g+0..3
            int cb = ca + 2;                   // chunk with k = 16kk+4g+8..11
            float4 a0l = *(const float4*)&As[cur][(size_t)ar * 32 + (ca ^ swz) * 4];
            float4 a0h = *(const float4*)&As[cur][(size_t)ar * 32 + (cb ^ swz) * 4];
            float4 a1l = *(const float4*)&As[cur][(size_t)(ar + 32) * 32 + (ca ^ swz) * 4];
            float4 a1h = *(const float4*)&As[cur][(size_t)(ar + 32) * 32 + (cb ^ swz) * 4];
            half8v a0 = { (_Float16)a0l.x, (_Float16)a0l.y, (_Float16)a0l.z, (_Float16)a0l.w,
                          (_Float16)a0h.x, (_Float16)a0h.y, (_Float16)a0h.z, (_Float16)a0h.w };
            half8v a1 = { (_Float16)a1l.x, (_Float16)a1l.y, (_Float16)a1l.z, (_Float16)a1l.w,
                          (_Float16)a1h.x, (_Float16)a1h.y, (_Float16)a1h.z, (_Float16)a1h.w };
            const _Float16* bp = Bb + (t * 2 + kk) * 16;
            half8v b0 = *(const half8v*)bp;
            half8v b1 = *(const half8v*)(bp + (size_t)32 * NF);
            acc[0][0] = __builtin_amdgcn_mfma_f32_32x32x16_f16(a0, b0, acc[0][0], 0, 0, 0);
            acc[0][1] = __builtin_amdgcn_mfma_f32_32x32x16_f16(a0, b1, acc[0][1], 0, 0, 0);
            acc[1][0] = __builtin_amdgcn_mfma_f32_32x32x16_f16(a1, b0, acc[1][0], 0, 0, 0);
            acc[1][1] = __builtin_amdgcn_mfma_f32_32x32x16_f16(a1, b1, acc[1][1], 0, 0, 0);
        }
        __builtin_amdgcn_s_barrier();          // all reads of As[cur] done before t+2 stage
    }

    // epilogue: D row = (r&3)+8*(r>>2)+4*(l>>5), col = l&31; scale by ns[row]
    const int cpos = pos16(l & 15);
    const int chi = ((l >> 4) & 1) << 4;
    #pragma unroll
    for (int m = 0; m < 2; ++m) {
        #pragma unroll
        for (int r = 0; r < 16; ++r) {
            int rloc = wr * 64 + m * 32 + (r & 3) + ((r >> 2) << 3) + ((l >> 5) << 2);
            int grow = row0 + rloc;
            if (grow < N) {
                float s = norm_s[grow];
                #pragma unroll
                for (int n = 0; n < 2; ++n) {
                    int colbase = wc * 64 + n * 32 + chi;
                    Cout[(size_t)grow * NH + colbase + cpos] = (_Float16)(acc[m][n][r] * s);
                }
            }
        }
    }
}

// ---------------- fused gather + layer-1 epilogue + z-dot, one wave/node ----
// z[w] = dot(relu(agg*nd + b1p)*ns, v2p); unroll-16, scalarized row_ptr
__global__ __launch_bounds__(512)
void gatherz_kernel(const _Float16* __restrict__ m, const int* __restrict__ row_ptr,
                    const int* __restrict__ col, const float* __restrict__ norm_d,
                    const float* __restrict__ norm_s, const float* __restrict__ b1p,
                    const float* __restrict__ v2p, float* __restrict__ z, int N) {
    int w = (blockIdx.x * 512 + threadIdx.x) >> 6;
    int lane = threadIdx.x & 63;
    if (w >= N) return;
    int beg = __builtin_amdgcn_readfirstlane(row_ptr[w]);
    int end = __builtin_amdgcn_readfirstlane(row_ptr[w + 1]);
    const unsigned* mu = (const unsigned*)m + lane;  // lane's column slot
    float ax = 0.f, ay = 0.f;
    int i = beg;
    for (; i + 15 < end; i += 16) {
        unsigned u[16];
        #pragma unroll
        for (int j = 0; j < 16; ++j) u[j] = mu[(size_t)col[i + j] * 64];
        #pragma unroll
        for (int j = 0; j < 16; ++j) { float2 v = h2f2(u[j]); ax += v.x; ay += v.y; }
    }
    for (; i + 3 < end; i += 4) {
        unsigned u[4];
        #pragma unroll
        for (int j = 0; j < 4; ++j) u[j] = mu[(size_t)col[i + j] * 64];
        #pragma unroll
        for (int j = 0; j < 4; ++j) { float2 v = h2f2(u[j]); ax += v.x; ay += v.y; }
    }
    for (; i < end; ++i) {
        float2 v = h2f2(mu[(size_t)col[i] * 64]);
        ax += v.x; ay += v.y;
    }
    float nd = norm_d[w], ns = norm_s[w];
    float2 bv = ((const float2*)b1p)[lane];
    float hx = fmaxf(fmaf(ax, nd, bv.x), 0.f) * ns;
    float hy = fmaxf(fmaf(ay, nd, bv.y), 0.f) * ns;
    float2 w2 = ((const float2*)v2p)[lane];
    float p = fmaf(hx, w2.x, hy * w2.y);
    #pragma unroll
    for (int off = 32; off > 0; off >>= 1) p += __shfl_down(p, off);
    if (lane == 0) z[w] = p;
}

// ---------------- scalar CSR sum: out[w] = nd*sum z[col] + c0 ---------------
__global__ __launch_bounds__(256)
void outsum_kernel(const float* __restrict__ z, const int* __restrict__ row_ptr,
                   const int* __restrict__ col, const float* __restrict__ norm_d,
                   const float* __restrict__ c0, float* __restrict__ out, int N) {
    int w = blockIdx.x * 256 + threadIdx.x;
    if (w >= N) return;
    int beg = row_ptr[w], end = row_ptr[w + 1];
    float s0 = 0.f, s1 = 0.f, s2 = 0.f, s3 = 0.f;
    int i = beg;
    for (; i + 3 < end; i += 4) {
        s0 += z[col[i]];     s1 += z[col[i + 1]];
        s2 += z[col[i + 2]]; s3 += z[col[i + 3]];
    }
    for (; i < end; ++i) s0 += z[col[i]];
    out[w] = norm_d[w] * ((s0 + s1) + (s2 + s3)) + c0[0];
}

extern "C" void kernel_launch(void* const* d_in, const int* in_sizes, int n_in,
                              void* d_out, int out_size, void* d_ws, size_t ws_size,
                              hipStream_t stream) {
    const float* x   = (const float*)d_in[0];
    const float* W1  = (const float*)d_in[1];
    const float* b1  = (const float*)d_in[2];
    const float* W2  = (const float*)d_in[3];
    const float* b2  = (const float*)d_in[4];
    const float* Wfc = (const float*)d_in[5];
    const float* bfc = (const float*)d_in[6];
    const int*   src = (const int*)d_in[7];
    const int*   dst = (const int*)d_in[8];
    float* out = (float*)d_out;

    const int N = NNODES, E = NEDGES;

    // workspace layout (all offsets 16B-aligned)
    char* p = (char*)d_ws;
    float*    norm_s = (float*)p;      p += (size_t)N * 4;
    float*    norm_d = (float*)p;      p += (size_t)N * 4;
    _Float16* bufA_h = (_Float16*)p;   p += (size_t)N * NH * 2;   // m1 (25.6 MB)
    _Float16* Wt1    = (_Float16*)p;   p += (size_t)NF * NH * 2;
    float*    b1p    = (float*)p;      p += NH * 4;
    float*    v2p    = (float*)p;      p += NH * 4;
    float*    c0     = (float*)p;      p += 16;
    float*    z      = (float*)p;      p += (size_t)N * 4;
    int*      cnt_in = (int*)p;        p += (size_t)N * 4;
    int*      row_ptr= (int*)p;        p += (size_t)(N + 1) * 4 + 12;  // keep 16B align
    int*      col    = (int*)p;        p += (size_t)E * 4;
    int*      bsum   = (int*)p;        p += 128 * 4;
    unsigned* partial= (unsigned*)p;   // HG * HWORDS * 4 = 40 MB
    // offb (20 MB) aliases bufA_h (25.6 MB): dead before gemm1 writes bufA_h.
    unsigned char* offb = (unsigned char*)bufA_h;

    // ---- CSR build + norms + weight prep (zero global atomics) ----
    hist_part_kernel<<<HG, 512, 0, stream>>>(src, dst, partial);
    degscan_kernel<<<(HWORDS + 255) / 256, 256, 0, stream>>>(partial, offb, norm_s, norm_d, cnt_in);
    scanA_kernel<<<SCAN_NBLK, 256, 0, stream>>>(cnt_in, row_ptr, bsum, N);
    scanB_kernel<<<1, 128, 0, stream>>>(bsum, SCAN_NBLK, row_ptr);
    scanC_kernel<<<SCAN_NBLK, 256, 0, stream>>>(row_ptr, bsum, N);
    fill_kernel<<<HG, 512, 0, stream>>>(src, dst, row_ptr, offb, col);
    prep_w_kernel<<<WPREP_BLOCKS + 1, 256, 0, stream>>>(W1, b1, Wt1, b1p,
                                                        W2, Wfc, b2, bfc, v2p, c0);

    // ---- layer 1 GEMM (convx fused, dbuf+counted-vmcnt): m1 = (x @ W1) * ns ----
    gemm1_kernel<<<(N + 127) / 128, 256, 0, stream>>>(x, Wt1, norm_s, bufA_h, N);
    // ---- fused: agg1 -> h -> z (layer 2 collapsed into v2 dot) ----
    gatherz_kernel<<<((size_t)N * 64 + 511) / 512, 512, 0, stream>>>(
        bufA_h, row_ptr, col, norm_d, norm_s, b1p, v2p, z, N);
    // ---- out[w] = nd * sum z[col] + c0 ----
    outsum_kernel<<<(N + 255) / 256, 256, 0, stream>>>(z, row_ptr, col, norm_d, c0, out, N);
}

// Round 17
// 194.780 us; speedup vs baseline: 1.4653x; 1.0130x over previous
//
#include <hip/hip_runtime.h>
#include <hip/hip_bf16.h>

#define NNODES 100000
#define NEDGES 1600000
#define NF 256
#define NH 128
#define SCAN_ELEMS 1024
#define SCAN_NBLK ((NNODES + SCAN_ELEMS - 1) / SCAN_ELEMS)   // 98

// LDS-privatized histogram / fill parameters
#define HG 200                     // workgroups (chunks)
#define HCHUNK (NEDGES / HG)       // 8000 edges per WG
#define HBINS 50000                // nodes per pass (100 KB LDS)
#define HR 2                       // passes (2 * 50000 = 100000)
#define HWORDS (NNODES / 2)        // 50000 packed words per partial slice

#define WPREP_BLOCKS 129           // (NF*NH + NH + 255)/256

typedef _Float16 half4v __attribute__((ext_vector_type(4)));
typedef _Float16 half8v __attribute__((ext_vector_type(8)));
typedef float floatx16 __attribute__((ext_vector_type(16)));

// k-permutation within each 16-block so MFMA f16 fragments (k = g*4 + (j&3) + 8*(j>>2))
// are 8 contiguous halves in storage. perm: [0,1,2,3, 8,9,10,11, 4,5,6,7, 12,13,14,15]
__device__ __forceinline__ int pos16(int k) {        // logical k (0..15) -> storage pos
    return (((k >> 2) & 1) << 3) + (k & 3) + (((k >> 3) & 1) << 2);
}
__device__ __forceinline__ int ipos16(int p) {       // storage pos -> logical k
    int g = (p >> 3) & 1, j = p & 7;
    return g * 4 + (j & 3) + ((j >> 2) << 3);
}

__device__ __forceinline__ float2 h2f2(unsigned u) {
    union { unsigned u; _Float16 h[2]; } c; c.u = u;
    return make_float2((float)c.h[0], (float)c.h[1]);
}

// async global->LDS DMA, 16 B per lane; LDS dest = wave base + lane*16 (linear)
__device__ __forceinline__ void load_lds16(const void* g, void* l) {
    __builtin_amdgcn_global_load_lds(
        (const __attribute__((address_space(1))) void*)g,
        (__attribute__((address_space(3))) void*)l, 16, 0, 0);
}

// ---------------- LDS-privatized degree histogram (2 passes) ----------------
__global__ __launch_bounds__(512)
void hist_part_kernel(const int* __restrict__ src, const int* __restrict__ dst,
                      unsigned* __restrict__ partial) {
    __shared__ unsigned lds[HBINS / 2];        // 25000 words = 100 KB
    const int g = blockIdx.x, t = threadIdx.x;
    const int e0 = g * HCHUNK;
    for (int r = 0; r < HR; ++r) {
        const int lo = r * HBINS;
        for (int i = t; i < HBINS / 2; i += 512) lds[i] = 0;
        __syncthreads();
        for (int i = t; i < HCHUNK; i += 512) {
            unsigned us = (unsigned)(src[e0 + i] - lo);
            if (us < HBINS) atomicAdd(&lds[us >> 1], 1u << ((us & 1) * 16));
            unsigned ud = (unsigned)(dst[e0 + i] - lo);
            if (ud < HBINS) atomicAdd(&lds[ud >> 1], 1u << ((ud & 1) * 16 + 8));
        }
        __syncthreads();
        unsigned* dp = partial + (size_t)g * HWORDS + (lo >> 1);
        for (int i = t; i < HBINS / 2; i += 512) dp[i] = lds[i];
        __syncthreads();
    }
}

// ---------------- fused: per-chunk exclusive scan + degree reduce + norms ----
// unroll-8: 8 strided L3 reads in flight; u16-packed offb store
__global__ __launch_bounds__(256)
void degscan_kernel(const unsigned* __restrict__ partial,
                    unsigned char* __restrict__ offb,
                    float* __restrict__ ns, float* __restrict__ nd,
                    int* __restrict__ cnt_in) {
    int w = blockIdx.x * 256 + threadIdx.x;
    if (w >= HWORDS) return;
    unsigned o0 = 0, i0 = 0, o1 = 0, i1 = 0;
    for (int g0 = 0; g0 < HG; g0 += 8) {
        unsigned v[8];
        #pragma unroll
        for (int j = 0; j < 8; ++j) v[j] = partial[(size_t)(g0 + j) * HWORDS + w];
        #pragma unroll
        for (int j = 0; j < 8; ++j) {
            *(unsigned short*)(offb + (size_t)(g0 + j) * NNODES + 2 * w) =
                (unsigned short)((i0 & 0xffu) | ((i1 & 0xffu) << 8));
            o0 += v[j] & 0xffu;         i0 += (v[j] >> 8) & 0xffu;
            o1 += (v[j] >> 16) & 0xffu; i1 += v[j] >> 24;
        }
    }
    int n0 = 2 * w, n1 = 2 * w + 1;
    ns[n0] = rsqrtf((float)max((int)o0, 1));
    nd[n0] = rsqrtf((float)max((int)i0, 1));
    cnt_in[n0] = (int)i0;
    ns[n1] = rsqrtf((float)max((int)o1, 1));
    nd[n1] = rsqrtf((float)max((int)i1, 1));
    cnt_in[n1] = (int)i1;
}

// ---------------- 3-pass exclusive scan over cnt_in -> row_ptr --------------
__global__ __launch_bounds__(256)
void scanA_kernel(const int* __restrict__ cnt, int* __restrict__ pre,
                  int* __restrict__ bsum, int n) {
    __shared__ int tsum[256];
    int b = blockIdx.x, t = threadIdx.x;
    int base = b * SCAN_ELEMS + t * 4;
    int v[4]; int s = 0;
    #pragma unroll
    for (int k = 0; k < 4; ++k) { int idx = base + k; v[k] = (idx < n) ? cnt[idx] : 0; s += v[k]; }
    tsum[t] = s;
    __syncthreads();
    for (int off = 1; off < 256; off <<= 1) {
        int val = (t >= off) ? tsum[t - off] : 0;
        __syncthreads();
        tsum[t] += val;
        __syncthreads();
    }
    int run = (t == 0) ? 0 : tsum[t - 1];
    #pragma unroll
    for (int k = 0; k < 4; ++k) { int idx = base + k; if (idx < n) pre[idx] = run; run += v[k]; }
    if (t == 255) bsum[b] = tsum[255];
}

__global__ __launch_bounds__(128)
void scanB_kernel(int* __restrict__ bsum, int nb, int* __restrict__ row_ptr) {
    __shared__ int s[128];
    int t = threadIdx.x;
    int v = (t < nb) ? bsum[t] : 0;
    s[t] = v;
    __syncthreads();
    for (int off = 1; off < 128; off <<= 1) {
        int u = (t >= off) ? s[t - off] : 0;
        __syncthreads();
        s[t] += u;
        __syncthreads();
    }
    if (t < nb) bsum[t] = s[t] - v;           // exclusive block sums
    if (t == 0) row_ptr[NNODES] = NEDGES;
}

__global__ __launch_bounds__(256)
void scanC_kernel(int* __restrict__ pre, const int* __restrict__ bsum, int n) {
    int add = bsum[blockIdx.x];
    int base = blockIdx.x * SCAN_ELEMS + threadIdx.x;
    #pragma unroll
    for (int k = 0; k < 4; ++k) {
        int idx = base + k * 256;
        if (idx < n) pre[idx] += add;
    }
}

// ---------------- atomic-free bucket fill (2 passes) ------------------------
__global__ __launch_bounds__(512)
void fill_kernel(const int* __restrict__ src, const int* __restrict__ dst,
                 const int* __restrict__ row_ptr, const unsigned char* __restrict__ offb,
                 int* __restrict__ col) {
    __shared__ unsigned lcur[HBINS / 2];       // 25000 words, 2x16-bit counters
    const int g = blockIdx.x, t = threadIdx.x;
    const int e0 = g * HCHUNK;
    const unsigned char* ob = offb + (size_t)g * NNODES;
    for (int r = 0; r < HR; ++r) {
        const int lo = r * HBINS;
        for (int i = t; i < HBINS / 2; i += 512) lcur[i] = 0;
        __syncthreads();
        for (int i = t; i < HCHUNK; i += 512) {
            int d = dst[e0 + i];
            unsigned ud = (unsigned)(d - lo);
            if (ud < HBINS) {
                unsigned prev = atomicAdd(&lcur[ud >> 1], 1u << ((ud & 1) * 16));
                unsigned rank = (prev >> ((ud & 1) * 16)) & 0xffffu;
                int p = row_ptr[d] + (int)ob[d] + (int)rank;
                col[p] = src[e0 + i];
            }
        }
        __syncthreads();
    }
}

// ---------------- weight prep: W1 transpose+perm, b1 perm, v2 = W2@Wfc, c0 --
__global__ __launch_bounds__(256)
void prep_w_kernel(const float* __restrict__ W1, const float* __restrict__ b1,
                   _Float16* __restrict__ Wt1, float* __restrict__ b1p,
                   const float* __restrict__ W2, const float* __restrict__ Wfc,
                   const float* __restrict__ b2, const float* __restrict__ bfc,
                   float* __restrict__ v2p, float* __restrict__ c0) {
    int b = blockIdx.x, t = threadIdx.x;
    if (b < WPREP_BLOCKS) {
        int id = b * 256 + t;
        if (id < NF * NH) {                    // W1 -> Wt1[n][perm(k)] f16
            int k = id >> 7, n = id & 127;
            Wt1[(size_t)n * NF + (k & ~15) + pos16(k & 15)] = (_Float16)W1[id];
        } else if (id < NF * NH + NH) {
            int pos = id - NF * NH;
            int k = (pos & ~15) + ipos16(pos & 15);
            b1p[pos] = b1[k];
        }
    } else {
        // v2 = W2 @ Wfc (perm order), c0 = b2.Wfc + bfc
        if (t < 128) {
            float s = 0.f;
            #pragma unroll 16
            for (int j = 0; j < 128; ++j) s += W2[t * 128 + j] * Wfc[j];
            v2p[(t & ~15) + pos16(t & 15)] = s;
        } else if (t < 192) {
            int lane = t - 128;
            float c = b2[lane] * Wfc[lane] + b2[lane + 64] * Wfc[lane + 64];
            #pragma unroll
            for (int off = 32; off > 0; off >>= 1) c += __shfl_down(c, off);
            if (lane == 0) c0[0] = c + bfc[0];
        }
    }
}

// ---------------- fused GEMM1: C = (x @ W1) * ns ----------------------------
// 64-row x 2-wave blocks (1563 blocks, 16 KB LDS, VGPR~64 -> ~6-10 resident
// independent streams/CU vs 4 before): TLP now covers the ~2000-cycle loaded
// DMA latency that pinned all 128-row variants at ~60 us. BK=32 double-buffer,
// counted vmcnt(4) + raw s_barrier (loads stay in flight across barriers),
// rows clamped so every wave issues exactly 4 DMAs (uniform vmcnt).
__global__ __launch_bounds__(128, 4)
void gemm1_kernel(const float* __restrict__ X, const _Float16* __restrict__ Wt,
                  const float* __restrict__ norm_s, _Float16* __restrict__ Cout,
                  int N) {
    __shared__ __align__(16) float As[2][64 * 32];    // 2 x 8 KB
    const int tid = threadIdx.x;
    const int l = tid & 63, w = tid >> 6;      // 2 waves; wc = w
    const int wc = w;
    const int row0 = blockIdx.x * 64;

    const _Float16* Bb = Wt + (size_t)(wc * 64 + (l & 31)) * NF + (l >> 5) * 8;
    const int ar = l & 31;                     // A rows ar, ar+32
    const int swz = ar & 7;                    // (ar+32)&7 == ar&7
    const int g = l >> 5;
    const int lr = l >> 3, lc = l & 7;         // staging: 8 rows/DMA, 8 chunks/row
    floatx16 acc[2][2] = {};

    // prologue: stage slab 0 into buf 0 (4 DMAs/wave, rows clamped)
    #pragma unroll
    for (int i = 0; i < 4; ++i) {
        int R = w * 32 + i * 8;
        int r = R + lr;
        int grow = min(row0 + r, N - 1);
        int srcc = lc ^ (r & 7);
        load_lds16(X + (size_t)grow * NF + srcc * 4, &As[0][R * 32]);
    }

    for (int t = 0; t < 8; ++t) {
        const int cur = t & 1;
        if (t < 7) {
            #pragma unroll
            for (int i = 0; i < 4; ++i) {
                int R = w * 32 + i * 8;
                int r = R + lr;
                int grow = min(row0 + r, N - 1);
                int srcc = lc ^ (r & 7);
                load_lds16(X + (size_t)grow * NF + (t + 1) * 32 + srcc * 4,
                           &As[cur ^ 1][R * 32]);
            }
            __builtin_amdgcn_sched_barrier(0);
            asm volatile("s_waitcnt vmcnt(4)" ::: "memory");   // slab t done; t+1 in flight
            __builtin_amdgcn_sched_barrier(0);
        } else {
            __builtin_amdgcn_sched_barrier(0);
            asm volatile("s_waitcnt vmcnt(0)" ::: "memory");
            __builtin_amdgcn_sched_barrier(0);
        }
        __builtin_amdgcn_s_barrier();          // raw: no implicit vmcnt(0) drain
        #pragma unroll
        for (int kk = 0; kk < 2; ++kk) {
            int ca = kk * 4 + g;               // chunk with k = 16kk+4g+0..3
            int cb = ca + 2;                   // chunk with k = 16kk+4g+8..11
            float4 a0l = *(const float4*)&As[cur][(size_t)ar * 32 + (ca ^ swz) * 4];
            float4 a0h = *(const float4*)&As[cur][(size_t)ar * 32 + (cb ^ swz) * 4];
            float4 a1l = *(const float4*)&As[cur][(size_t)(ar + 32) * 32 + (ca ^ swz) * 4];
            float4 a1h = *(const float4*)&As[cur][(size_t)(ar + 32) * 32 + (cb ^ swz) * 4];
            half8v a0 = { (_Float16)a0l.x, (_Float16)a0l.y, (_Float16)a0l.z, (_Float16)a0l.w,
                          (_Float16)a0h.x, (_Float16)a0h.y, (_Float16)a0h.z, (_Float16)a0h.w };
            half8v a1 = { (_Float16)a1l.x, (_Float16)a1l.y, (_Float16)a1l.z, (_Float16)a1l.w,
                          (_Float16)a1h.x, (_Float16)a1h.y, (_Float16)a1h.z, (_Float16)a1h.w };
            const _Float16* bp = Bb + (t * 2 + kk) * 16;
            half8v b0 = *(const half8v*)bp;
            half8v b1 = *(const half8v*)(bp + (size_t)32 * NF);
            acc[0][0] = __builtin_amdgcn_mfma_f32_32x32x16_f16(a0, b0, acc[0][0], 0, 0, 0);
            acc[0][1] = __builtin_amdgcn_mfma_f32_32x32x16_f16(a0, b1, acc[0][1], 0, 0, 0);
            acc[1][0] = __builtin_amdgcn_mfma_f32_32x32x16_f16(a1, b0, acc[1][0], 0, 0, 0);
            acc[1][1] = __builtin_amdgcn_mfma_f32_32x32x16_f16(a1, b1, acc[1][1], 0, 0, 0);
        }
        __builtin_amdgcn_s_barrier();          // all reads of As[cur] done before t+2 stage
    }

    // epilogue: D row = (r&3)+8*(r>>2)+4*(l>>5), col = l&31; scale by ns[row]
    const int cpos = pos16(l & 15);
    const int chi = ((l >> 4) & 1) << 4;
    #pragma unroll
    for (int m = 0; m < 2; ++m) {
        #pragma unroll
        for (int r = 0; r < 16; ++r) {
            int rloc = m * 32 + (r & 3) + ((r >> 2) << 3) + ((l >> 5) << 2);
            int grow = row0 + rloc;
            if (grow < N) {
                float s = norm_s[grow];
                #pragma unroll
                for (int n = 0; n < 2; ++n) {
                    int colbase = wc * 64 + n * 32 + chi;
                    Cout[(size_t)grow * NH + colbase + cpos] = (_Float16)(acc[m][n][r] * s);
                }
            }
        }
    }
}

// ---------------- fused gather + layer-1 epilogue + z-dot, one wave/node ----
// z[w] = dot(relu(agg*nd + b1p)*ns, v2p); unroll-16, scalarized row_ptr
__global__ __launch_bounds__(512)
void gatherz_kernel(const _Float16* __restrict__ m, const int* __restrict__ row_ptr,
                    const int* __restrict__ col, const float* __restrict__ norm_d,
                    const float* __restrict__ norm_s, const float* __restrict__ b1p,
                    const float* __restrict__ v2p, float* __restrict__ z, int N) {
    int w = (blockIdx.x * 512 + threadIdx.x) >> 6;
    int lane = threadIdx.x & 63;
    if (w >= N) return;
    int beg = __builtin_amdgcn_readfirstlane(row_ptr[w]);
    int end = __builtin_amdgcn_readfirstlane(row_ptr[w + 1]);
    const unsigned* mu = (const unsigned*)m + lane;  // lane's column slot
    float ax = 0.f, ay = 0.f;
    int i = beg;
    for (; i + 15 < end; i += 16) {
        unsigned u[16];
        #pragma unroll
        for (int j = 0; j < 16; ++j) u[j] = mu[(size_t)col[i + j] * 64];
        #pragma unroll
        for (int j = 0; j < 16; ++j) { float2 v = h2f2(u[j]); ax += v.x; ay += v.y; }
    }
    for (; i + 3 < end; i += 4) {
        unsigned u[4];
        #pragma unroll
        for (int j = 0; j < 4; ++j) u[j] = mu[(size_t)col[i + j] * 64];
        #pragma unroll
        for (int j = 0; j < 4; ++j) { float2 v = h2f2(u[j]); ax += v.x; ay += v.y; }
    }
    for (; i < end; ++i) {
        float2 v = h2f2(mu[(size_t)col[i] * 64]);
        ax += v.x; ay += v.y;
    }
    float nd = norm_d[w], ns = norm_s[w];
    float2 bv = ((const float2*)b1p)[lane];
    float hx = fmaxf(fmaf(ax, nd, bv.x), 0.f) * ns;
    float hy = fmaxf(fmaf(ay, nd, bv.y), 0.f) * ns;
    float2 w2 = ((const float2*)v2p)[lane];
    float p = fmaf(hx, w2.x, hy * w2.y);
    #pragma unroll
    for (int off = 32; off > 0; off >>= 1) p += __shfl_down(p, off);
    if (lane == 0) z[w] = p;
}

// ---------------- scalar CSR sum: out[w] = nd*sum z[col] + c0 ---------------
__global__ __launch_bounds__(256)
void outsum_kernel(const float* __restrict__ z, const int* __restrict__ row_ptr,
                   const int* __restrict__ col, const float* __restrict__ norm_d,
                   const float* __restrict__ c0, float* __restrict__ out, int N) {
    int w = blockIdx.x * 256 + threadIdx.x;
    if (w >= N) return;
    int beg = row_ptr[w], end = row_ptr[w + 1];
    float s0 = 0.f, s1 = 0.f, s2 = 0.f, s3 = 0.f;
    int i = beg;
    for (; i + 3 < end; i += 4) {
        s0 += z[col[i]];     s1 += z[col[i + 1]];
        s2 += z[col[i + 2]]; s3 += z[col[i + 3]];
    }
    for (; i < end; ++i) s0 += z[col[i]];
    out[w] = norm_d[w] * ((s0 + s1) + (s2 + s3)) + c0[0];
}

extern "C" void kernel_launch(void* const* d_in, const int* in_sizes, int n_in,
                              void* d_out, int out_size, void* d_ws, size_t ws_size,
                              hipStream_t stream) {
    const float* x   = (const float*)d_in[0];
    const float* W1  = (const float*)d_in[1];
    const float* b1  = (const float*)d_in[2];
    const float* W2  = (const float*)d_in[3];
    const float* b2  = (const float*)d_in[4];
    const float* Wfc = (const float*)d_in[5];
    const float* bfc = (const float*)d_in[6];
    const int*   src = (const int*)d_in[7];
    const int*   dst = (const int*)d_in[8];
    float* out = (float*)d_out;

    const int N = NNODES, E = NEDGES;

    // workspace layout (all offsets 16B-aligned)
    char* p = (char*)d_ws;
    float*    norm_s = (float*)p;      p += (size_t)N * 4;
    float*    norm_d = (float*)p;      p += (size_t)N * 4;
    _Float16* bufA_h = (_Float16*)p;   p += (size_t)N * NH * 2;   // m1 (25.6 MB)
    _Float16* Wt1    = (_Float16*)p;   p += (size_t)NF * NH * 2;
    float*    b1p    = (float*)p;      p += NH * 4;
    float*    v2p    = (float*)p;      p += NH * 4;
    float*    c0     = (float*)p;      p += 16;
    float*    z      = (float*)p;      p += (size_t)N * 4;
    int*      cnt_in = (int*)p;        p += (size_t)N * 4;
    int*      row_ptr= (int*)p;        p += (size_t)(N + 1) * 4 + 12;  // keep 16B align
    int*      col    = (int*)p;        p += (size_t)E * 4;
    int*      bsum   = (int*)p;        p += 128 * 4;
    unsigned* partial= (unsigned*)p;   // HG * HWORDS * 4 = 40 MB
    // offb (20 MB) aliases bufA_h (25.6 MB): dead before gemm1 writes bufA_h.
    unsigned char* offb = (unsigned char*)bufA_h;

    // ---- CSR build + norms + weight prep (zero global atomics) ----
    hist_part_kernel<<<HG, 512, 0, stream>>>(src, dst, partial);
    degscan_kernel<<<(HWORDS + 255) / 256, 256, 0, stream>>>(partial, offb, norm_s, norm_d, cnt_in);
    scanA_kernel<<<SCAN_NBLK, 256, 0, stream>>>(cnt_in, row_ptr, bsum, N);
    scanB_kernel<<<1, 128, 0, stream>>>(bsum, SCAN_NBLK, row_ptr);
    scanC_kernel<<<SCAN_NBLK, 256, 0, stream>>>(row_ptr, bsum, N);
    fill_kernel<<<HG, 512, 0, stream>>>(src, dst, row_ptr, offb, col);
    prep_w_kernel<<<WPREP_BLOCKS + 1, 256, 0, stream>>>(W1, b1, Wt1, b1p,
                                                        W2, Wfc, b2, bfc, v2p, c0);

    // ---- layer 1 GEMM (convx fused, 64-row 2-wave dbuf): m1 = (x @ W1) * ns ----
    gemm1_kernel<<<(N + 63) / 64, 128, 0, stream>>>(x, Wt1, norm_s, bufA_h, N);
    // ---- fused: agg1 -> h -> z (layer 2 collapsed into v2 dot) ----
    gatherz_kernel<<<((size_t)N * 64 + 511) / 512, 512, 0, stream>>>(
        bufA_h, row_ptr, col, norm_d, norm_s, b1p, v2p, z, N);
    // ---- out[w] = nd * sum z[col] + c0 ----
    outsum_kernel<<<(N + 255) / 256, 256, 0, stream>>>(z, row_ptr, col, norm_d, c0, out, N);
}